// Round 1
// baseline (791.003 us; speedup 1.0000x reference)
//
#include <hip/hip_runtime.h>

#define LEAKY(x) ((x) > 0.0f ? (x) : 0.01f * (x))

// ---------------- reductions / builds ----------------

__global__ void k_dmax(const float* __restrict__ deadline, float* __restrict__ dmax) {
    __shared__ float red[256];
    int t = threadIdx.x;
    float m = -1e30f;
    for (int i = t; i < 16384; i += 256) m = fmaxf(m, deadline[i]);
    red[t] = m; __syncthreads();
    for (int s = 128; s > 0; s >>= 1) {
        if (t < s) red[t] = fmaxf(red[t], red[t + s]);
        __syncthreads();
    }
    if (t == 0) *dmax = red[0];
}

__global__ void k_buildX(const float* __restrict__ loc, const float* __restrict__ deadline,
                         const float* __restrict__ dmax, float* __restrict__ X) {
    int i = blockIdx.x * 256 + threadIdx.x;
    if (i < 16384) {
        X[i * 3 + 0] = loc[i * 2 + 0];
        X[i * 3 + 1] = loc[i * 2 + 1];
        X[i * 3 + 2] = deadline[i] / (*dmax);
    }
}

// one block per (b,i) row: write r=1/dist (0 on diag), rowsum, global amax
__global__ __launch_bounds__(256) void k_buildR(const float* __restrict__ X, float* __restrict__ R,
                                                float* __restrict__ rowsum,
                                                unsigned int* __restrict__ amax_bits) {
    int bi = blockIdx.x;              // b*512 + i
    int b = bi >> 9, i = bi & 511;
    int t = threadIdx.x;
    const float* Xb = X + b * 512 * 3;
    float xi0 = Xb[i * 3], xi1 = Xb[i * 3 + 1], xi2 = Xb[i * 3 + 2];
    float lsum = 0.f, lmax = 0.f;
    float* Rrow = R + (size_t)bi * 512;
    for (int j = t; j < 512; j += 256) {
        float d0 = xi0 - Xb[j * 3], d1 = xi1 - Xb[j * 3 + 1], d2 = xi2 - Xb[j * 3 + 2];
        float dd = d0 * d0 + d1 * d1 + d2 * d2;
        float r = (j == i) ? 0.f : rsqrtf(dd);
        Rrow[j] = r;
        lsum += r; lmax = fmaxf(lmax, r);
    }
    __shared__ float s1[256], s2[256];
    s1[t] = lsum; s2[t] = lmax; __syncthreads();
    for (int s = 128; s > 0; s >>= 1) {
        if (t < s) { s1[t] += s1[t + s]; s2[t] = fmaxf(s2[t], s2[t + s]); }
        __syncthreads();
    }
    if (t == 0) {
        rowsum[bi] = s1[0];
        atomicMax(amax_bits, __float_as_uint(s2[0]));   // all values >= 0
    }
}

// in place: R -> L,  L[b,i,j] = (i==j) ? rowsum/amax - 1 : -R/amax
__global__ void k_buildL(float* __restrict__ R, const float* __restrict__ rowsum,
                         const unsigned int* __restrict__ amax_bits) {
    size_t id = (size_t)blockIdx.x * 256 + threadIdx.x;   // 8.4M
    float inv = 1.0f / __uint_as_float(*amax_bits);
    size_t bi = id >> 9;
    int j = (int)(id & 511);
    int i = (int)(bi & 511);
    float a = R[id] * inv;
    R[id] = (i == j) ? (rowsum[bi] * inv - 1.0f) : -a;
}

__global__ void k_F0(const float* __restrict__ X, const float* __restrict__ Wi,
                     const float* __restrict__ bi_, float* __restrict__ F0) {
    int id = blockIdx.x * 256 + threadIdx.x;   // 16384*384
    int row = id / 384, c = id % 384;
    F0[id] = X[row * 3] * Wi[c] + X[row * 3 + 1] * Wi[384 + c] + X[row * 3 + 2] * Wi[768 + c] + bi_[c];
}

// ---------------- GEMM kernels (BM=64, BN=128, BK=16, 256 thr, 4x8 microtile) ----------------

// Y_{part}[:, kp*128:+128] = pow(F0, kp+1) @ W_g{kp}[part*384:(part+1)*384, :]
__global__ __launch_bounds__(256) void k_ygemm(
    const float* __restrict__ F0,
    const float* __restrict__ Wg1, const float* __restrict__ Wg2, const float* __restrict__ Wg3,
    float* __restrict__ Y0, float* __restrict__ Y1, float* __restrict__ Y2)
{
    const int t = threadIdx.x;
    const int tileM = blockIdx.x;        // 0..255
    const int combo = blockIdx.y;        // 0..8
    const int kp = combo / 3, part = combo % 3;
    const float* Wg = (kp == 0) ? Wg1 : (kp == 1 ? Wg2 : Wg3);
    const float* B = Wg + part * 384 * 128;
    float* Ybuf = (part == 0) ? Y0 : (part == 1 ? Y1 : Y2);

    __shared__ float As[16][65];
    __shared__ float Bs[16][128];
    const int tx = t & 15, ty = t >> 4;
    float acc[4][8];
#pragma unroll
    for (int i = 0; i < 4; i++)
#pragma unroll
        for (int j = 0; j < 8; j++) acc[i][j] = 0.f;

    const float* Aptr = F0 + (size_t)tileM * 64 * 384;
    const int arow = t >> 2, akq = (t & 3) << 2;

    for (int k0 = 0; k0 < 384; k0 += 16) {
        float4 av = *(const float4*)(Aptr + arow * 384 + k0 + akq);
        if (kp == 1) { av.x *= av.x; av.y *= av.y; av.z *= av.z; av.w *= av.w; }
        else if (kp == 2) {
            av.x = av.x * av.x * av.x; av.y = av.y * av.y * av.y;
            av.z = av.z * av.z * av.z; av.w = av.w * av.w * av.w;
        }
        As[akq + 0][arow] = av.x; As[akq + 1][arow] = av.y;
        As[akq + 2][arow] = av.z; As[akq + 3][arow] = av.w;
#pragma unroll
        for (int e = 0; e < 2; e++) {
            int idx = t + e * 256;
            int kk = idx >> 5, c4 = (idx & 31) << 2;
            *(float4*)&Bs[kk][c4] = *(const float4*)(B + (k0 + kk) * 128 + c4);
        }
        __syncthreads();
#pragma unroll
        for (int kk = 0; kk < 16; kk++) {
            float aa[4] = {As[kk][ty * 4 + 0], As[kk][ty * 4 + 1], As[kk][ty * 4 + 2], As[kk][ty * 4 + 3]};
            float4 b0 = *(const float4*)&Bs[kk][tx * 8];
            float4 b1 = *(const float4*)&Bs[kk][tx * 8 + 4];
            float bb[8] = {b0.x, b0.y, b0.z, b0.w, b1.x, b1.y, b1.z, b1.w};
#pragma unroll
            for (int i = 0; i < 4; i++)
#pragma unroll
                for (int j = 0; j < 8; j++) acc[i][j] += aa[i] * bb[j];
        }
        __syncthreads();
    }
    float* Cbase = Ybuf + (size_t)(tileM * 64) * 384 + kp * 128;
#pragma unroll
    for (int i = 0; i < 4; i++) {
        float4 v0 = make_float4(acc[i][0], acc[i][1], acc[i][2], acc[i][3]);
        float4 v1 = make_float4(acc[i][4], acc[i][5], acc[i][6], acc[i][7]);
        *(float4*)(Cbase + (ty * 4 + i) * 384 + tx * 8) = v0;
        *(float4*)(Cbase + (ty * 4 + i) * 384 + tx * 8 + 4) = v1;
    }
}

// Cio += L @ Bsrc   (per batch, M=512, N=384, K=512)
__global__ __launch_bounds__(256) void k_lgemm(
    const float* __restrict__ Lm, const float* __restrict__ Bsrc, float* __restrict__ Cio)
{
    const int t = threadIdx.x;
    const int tileM = blockIdx.x;   // 0..7
    const int tileN = blockIdx.y;   // 0..2
    const int b = blockIdx.z;       // 0..31
    const float* A = Lm + (size_t)b * 512 * 512 + (size_t)tileM * 64 * 512;
    const float* B = Bsrc + (size_t)b * 512 * 384 + tileN * 128;
    float* C = Cio + (size_t)b * 512 * 384 + (size_t)tileM * 64 * 384 + tileN * 128;

    __shared__ float As[16][65];
    __shared__ float Bs[16][128];
    const int tx = t & 15, ty = t >> 4;
    float acc[4][8];
#pragma unroll
    for (int i = 0; i < 4; i++)
#pragma unroll
        for (int j = 0; j < 8; j++) acc[i][j] = 0.f;

    const int arow = t >> 2, akq = (t & 3) << 2;
    for (int k0 = 0; k0 < 512; k0 += 16) {
        float4 av = *(const float4*)(A + arow * 512 + k0 + akq);
        As[akq + 0][arow] = av.x; As[akq + 1][arow] = av.y;
        As[akq + 2][arow] = av.z; As[akq + 3][arow] = av.w;
#pragma unroll
        for (int e = 0; e < 2; e++) {
            int idx = t + e * 256;
            int kk = idx >> 5, c4 = (idx & 31) << 2;
            *(float4*)&Bs[kk][c4] = *(const float4*)(B + (size_t)(k0 + kk) * 384 + c4);
        }
        __syncthreads();
#pragma unroll
        for (int kk = 0; kk < 16; kk++) {
            float aa[4] = {As[kk][ty * 4 + 0], As[kk][ty * 4 + 1], As[kk][ty * 4 + 2], As[kk][ty * 4 + 3]};
            float4 b0 = *(const float4*)&Bs[kk][tx * 8];
            float4 b1 = *(const float4*)&Bs[kk][tx * 8 + 4];
            float bb[8] = {b0.x, b0.y, b0.z, b0.w, b1.x, b1.y, b1.z, b1.w};
#pragma unroll
            for (int i = 0; i < 4; i++)
#pragma unroll
                for (int j = 0; j < 8; j++) acc[i][j] += aa[i] * bb[j];
        }
        __syncthreads();
    }
#pragma unroll
    for (int i = 0; i < 4; i++) {
        float* cp = C + (size_t)(ty * 4 + i) * 384 + tx * 8;
        float4 o0 = *(float4*)cp;
        float4 o1 = *(float4*)(cp + 4);
        o0.x += acc[i][0]; o0.y += acc[i][1]; o0.z += acc[i][2]; o0.w += acc[i][3];
        o1.x += acc[i][4]; o1.y += acc[i][5]; o1.z += acc[i][6]; o1.w += acc[i][7];
        *(float4*)cp = o0;
        *(float4*)(cp + 4) = o1;
    }
}

// out_h rows 1..512: leaky(F1 @ WFs + beff)
__global__ __launch_bounds__(256) void k_fgemm(
    const float* __restrict__ F1, const float* __restrict__ WFs,
    const float* __restrict__ beff, float* __restrict__ out)
{
    const int t = threadIdx.x;
    const int tileM = blockIdx.x;   // 0..255
    __shared__ float As[16][65];
    __shared__ float Bs[16][128];
    const int tx = t & 15, ty = t >> 4;
    float acc[4][8];
#pragma unroll
    for (int i = 0; i < 4; i++)
#pragma unroll
        for (int j = 0; j < 8; j++) acc[i][j] = 0.f;

    const float* Aptr = F1 + (size_t)tileM * 64 * 384;
    const int arow = t >> 2, akq = (t & 3) << 2;
    for (int k0 = 0; k0 < 384; k0 += 16) {
        float4 av = *(const float4*)(Aptr + arow * 384 + k0 + akq);
        As[akq + 0][arow] = av.x; As[akq + 1][arow] = av.y;
        As[akq + 2][arow] = av.z; As[akq + 3][arow] = av.w;
#pragma unroll
        for (int e = 0; e < 2; e++) {
            int idx = t + e * 256;
            int kk = idx >> 5, c4 = (idx & 31) << 2;
            *(float4*)&Bs[kk][c4] = *(const float4*)(WFs + (k0 + kk) * 128 + c4);
        }
        __syncthreads();
#pragma unroll
        for (int kk = 0; kk < 16; kk++) {
            float aa[4] = {As[kk][ty * 4 + 0], As[kk][ty * 4 + 1], As[kk][ty * 4 + 2], As[kk][ty * 4 + 3]};
            float4 b0 = *(const float4*)&Bs[kk][tx * 8];
            float4 b1 = *(const float4*)&Bs[kk][tx * 8 + 4];
            float bb[8] = {b0.x, b0.y, b0.z, b0.w, b1.x, b1.y, b1.z, b1.w};
#pragma unroll
            for (int i = 0; i < 4; i++)
#pragma unroll
                for (int j = 0; j < 8; j++) acc[i][j] += aa[i] * bb[j];
        }
        __syncthreads();
    }
    float be[8];
#pragma unroll
    for (int j = 0; j < 8; j++) be[j] = beff[tx * 8 + j];
#pragma unroll
    for (int i = 0; i < 4; i++) {
        int row = tileM * 64 + ty * 4 + i;
        int b = row >> 9, n = row & 511;
        float* dst = out + (size_t)b * 65664 + (size_t)(n + 1) * 128 + tx * 8;
        float v[8];
#pragma unroll
        for (int j = 0; j < 8; j++) { float x = acc[i][j] + be[j]; v[j] = LEAKY(x); }
        *(float4*)dst = make_float4(v[0], v[1], v[2], v[3]);
        *(float4*)(dst + 4) = make_float4(v[4], v[5], v[6], v[7]);
    }
}

// ---------------- epilogue pieces ----------------

// F1 = leaky(G + b_cat) + F0, in place over F0
__global__ void k_F1(float* __restrict__ F0io, const float* __restrict__ G,
                     const float* __restrict__ bg1, const float* __restrict__ bg2,
                     const float* __restrict__ bg3) {
    int id = blockIdx.x * 256 + threadIdx.x;   // 16384*384
    int c = id % 384; int k = c >> 7; int cc = c & 127;
    float bb = (k == 0 ? bg1 : (k == 1 ? bg2 : bg3))[cc];
    float v = G[id] + bb;
    v = LEAKY(v);
    F0io[id] = v + F0io[id];
}

__global__ __launch_bounds__(384) void k_bnred(const float* __restrict__ F1,
                                               float* __restrict__ sum1, float* __restrict__ sum2) {
    int c = threadIdx.x;          // 0..383
    int r0 = blockIdx.x * 128;    // 128 blocks
    float s1 = 0.f, s2 = 0.f;
    for (int r = 0; r < 128; r++) {
        float v = F1[(size_t)(r0 + r) * 384 + c];
        s1 += v; s2 += v * v;
    }
    atomicAdd(&sum1[c], s1);
    atomicAdd(&sum2[c], s2);
}

__global__ void k_bnfin(const float* __restrict__ sum1, const float* __restrict__ sum2,
                        const float* __restrict__ gamma, const float* __restrict__ beta,
                        float* __restrict__ s, float* __restrict__ tt) {
    int c = threadIdx.x;   // 384
    float mu = sum1[c] * (1.f / 16384.f);
    float var = sum2[c] * (1.f / 16384.f) - mu * mu;
    float sc = gamma[c] / sqrtf(var + 1e-5f);
    s[c] = sc;
    tt[c] = beta[c] - mu * sc;
}

__global__ void k_fold(const float* __restrict__ WF, const float* __restrict__ s,
                       float* __restrict__ WFs) {
    int id = blockIdx.x * 256 + threadIdx.x;   // 49152
    WFs[id] = WF[id] * s[id >> 7];
}

__global__ void k_beff(const float* __restrict__ WF, const float* __restrict__ tt,
                       const float* __restrict__ bF, float* __restrict__ beff) {
    int o = threadIdx.x;   // 128
    float acc = bF[o];
    for (int c = 0; c < 384; c++) acc += tt[c] * WF[c * 128 + o];
    beff[o] = acc;
}

__global__ void k_depot(const float* __restrict__ depot, const float* __restrict__ Wd,
                        const float* __restrict__ bd, float* __restrict__ out) {
    int id = blockIdx.x * 256 + threadIdx.x;   // 4096
    int b = id >> 7, o = id & 127;
    out[(size_t)b * 65664 + o] = depot[b * 2] * Wd[o] + depot[b * 2 + 1] * Wd[128 + o] + bd[o];
}

__global__ void k_mean(const float* __restrict__ out_h, float* __restrict__ out_m) {
    int b = blockIdx.x, o = threadIdx.x;   // 32 x 128
    const float* hb = out_h + (size_t)b * 65664;
    float s = 0.f;
    for (int r = 0; r < 513; r++) s += hb[r * 128 + o];
    out_m[b * 128 + o] = s * (1.0f / 513.0f);
}

// ---------------- launch ----------------

extern "C" void kernel_launch(void* const* d_in, const int* in_sizes, int n_in,
                              void* d_out, int out_size, void* d_ws, size_t ws_size,
                              hipStream_t stream) {
    const float* loc      = (const float*)d_in[0];
    const float* deadline = (const float*)d_in[1];
    const float* depot    = (const float*)d_in[3];
    const float* W_init   = (const float*)d_in[4];
    const float* b_init   = (const float*)d_in[5];
    const float* W_dep    = (const float*)d_in[6];
    const float* b_dep    = (const float*)d_in[7];
    const float* W_g1     = (const float*)d_in[8];
    const float* b_g1     = (const float*)d_in[9];
    const float* W_g2     = (const float*)d_in[10];
    const float* b_g2     = (const float*)d_in[11];
    const float* W_g3     = (const float*)d_in[12];
    const float* b_g3     = (const float*)d_in[13];
    const float* gamma    = (const float*)d_in[14];
    const float* beta     = (const float*)d_in[15];
    const float* W_F      = (const float*)d_in[16];
    const float* b_F      = (const float*)d_in[17];
    float* out = (float*)d_out;
    float* ws  = (float*)d_ws;

    // workspace layout (floats); total ~33.74M floats ~= 135 MB
    float* X       = ws;                       // 49152
    float* dmax    = ws + 49152;               // 1
    unsigned int* amax = (unsigned int*)(ws + 49153);
    float* rowsum  = ws + 49160;               // 16384
    float* Lm      = ws + 131072;              // 8388608
    float* F0      = ws + 8519680;             // 6291456
    float* Y0      = ws + 14811136;            // 6291456
    float* Y1      = ws + 21102592;            // 6291456
    float* Y2      = ws + 27394048;            // 6291456
    float* bn1     = ws + 33685504;            // 384
    float* bn2     = ws + 33685888;            // 384
    float* sS      = ws + 33686272;            // 384
    float* sT      = ws + 33686656;            // 384
    float* WFs     = ws + 33687040;            // 49152
    float* beff    = ws + 33736192;            // 128

    hipMemsetAsync(amax, 0, 4, stream);
    hipMemsetAsync(bn1, 0, 2 * 384 * sizeof(float), stream);

    k_dmax<<<1, 256, 0, stream>>>(deadline, dmax);
    k_buildX<<<64, 256, 0, stream>>>(loc, deadline, dmax, X);
    k_buildR<<<16384, 256, 0, stream>>>(X, Lm, rowsum, amax);
    k_buildL<<<32768, 256, 0, stream>>>(Lm, rowsum, amax);
    k_F0<<<24576, 256, 0, stream>>>(X, W_init, b_init, F0);

    dim3 yg(256, 9);
    k_ygemm<<<yg, 256, 0, stream>>>(F0, W_g1, W_g2, W_g3, Y0, Y1, Y2);

    dim3 lg(8, 3, 32);
    k_lgemm<<<lg, 256, 0, stream>>>(Lm, Y2, Y1);   // Z = Y1 + L@Y2   (into Y1)
    k_lgemm<<<lg, 256, 0, stream>>>(Lm, Y1, Y0);   // G = Y0 + L@Z    (into Y0)

    k_F1<<<24576, 256, 0, stream>>>(F0, Y0, b_g1, b_g2, b_g3);   // F1 into F0 buffer

    k_bnred<<<128, 384, 0, stream>>>(F0, bn1, bn2);
    k_bnfin<<<1, 384, 0, stream>>>(bn1, bn2, gamma, beta, sS, sT);
    k_fold<<<192, 256, 0, stream>>>(W_F, sS, WFs);
    k_beff<<<1, 128, 0, stream>>>(W_F, sT, b_F, beff);

    k_fgemm<<<256, 256, 0, stream>>>(F0, WFs, beff, out);
    k_depot<<<16, 256, 0, stream>>>(depot, W_dep, b_dep, out);
    k_mean<<<32, 128, 0, stream>>>(out, out + 2101248);
}

// Round 2
// 311.689 us; speedup vs baseline: 2.5378x; 2.5378x over previous
//
#include <hip/hip_runtime.h>

#define LEAKY(x) ((x) > 0.0f ? (x) : 0.01f * (x))

typedef __attribute__((ext_vector_type(8))) short bf16x8;      // MFMA A/B frag (8 bf16)
typedef __attribute__((ext_vector_type(4))) float f32x4;       // MFMA C/D frag
typedef __attribute__((ext_vector_type(8))) unsigned short u16x8;
typedef __attribute__((ext_vector_type(4))) unsigned short u16x4;
typedef __attribute__((ext_vector_type(2))) unsigned short u16x2;

__device__ __forceinline__ unsigned short f2bf(float f) {
    unsigned int u = __float_as_uint(f);
    unsigned int r = (u + 0x7fffu + ((u >> 16) & 1u)) >> 16;   // RNE
    return (unsigned short)r;
}

// ---------------- small builds ----------------

__global__ void k_dmax(const float* __restrict__ deadline, float* __restrict__ dmax) {
    __shared__ float red[256];
    int t = threadIdx.x;
    float m = -1e30f;
    for (int i = t; i < 16384; i += 256) m = fmaxf(m, deadline[i]);
    red[t] = m; __syncthreads();
    for (int s = 128; s > 0; s >>= 1) {
        if (t < s) red[t] = fmaxf(red[t], red[t + s]);
        __syncthreads();
    }
    if (t == 0) *dmax = red[0];
}

__global__ void k_buildX(const float* __restrict__ loc, const float* __restrict__ deadline,
                         const float* __restrict__ dmax, float* __restrict__ X) {
    int i = blockIdx.x * 256 + threadIdx.x;
    if (i < 16384) {
        X[i * 3 + 0] = loc[i * 2 + 0];
        X[i * 3 + 1] = loc[i * 2 + 1];
        X[i * 3 + 2] = deadline[i] / (*dmax);
    }
}

// one wave per (b,i) row; no global atomics
__global__ __launch_bounds__(256) void k_buildR(const float* __restrict__ X, float* __restrict__ R,
                                                float* __restrict__ rowsum, float* __restrict__ pmax) {
    int blk = blockIdx.x;                       // 0..4095
    int wave = threadIdx.x >> 6, lane = threadIdx.x & 63;
    int bi = blk * 4 + wave;                    // b*512 + i
    int b = bi >> 9, i = bi & 511;
    const float* Xb = X + b * 1536;
    float xi0 = Xb[i * 3], xi1 = Xb[i * 3 + 1], xi2 = Xb[i * 3 + 2];
    float lsum = 0.f, lmax = 0.f;
    float* Rrow = R + (size_t)bi * 512;
    for (int j = lane; j < 512; j += 64) {
        float d0 = xi0 - Xb[j * 3], d1 = xi1 - Xb[j * 3 + 1], d2 = xi2 - Xb[j * 3 + 2];
        float dd = d0 * d0 + d1 * d1 + d2 * d2;
        float r = (j == i) ? 0.f : rsqrtf(dd);
        Rrow[j] = r;
        lsum += r; lmax = fmaxf(lmax, r);
    }
    for (int off = 32; off > 0; off >>= 1) {
        lsum += __shfl_down(lsum, off);
        lmax = fmaxf(lmax, __shfl_down(lmax, off));
    }
    __shared__ float smax[4];
    if (lane == 0) { rowsum[bi] = lsum; smax[wave] = lmax; }
    __syncthreads();
    if (threadIdx.x == 0) pmax[blk] = fmaxf(fmaxf(smax[0], smax[1]), fmaxf(smax[2], smax[3]));
}

__global__ void k_amax(const float* __restrict__ pmax, float* __restrict__ amaxf) {
    __shared__ float red[256];
    int t = threadIdx.x;
    float m = 0.f;
    for (int i = t; i < 4096; i += 256) m = fmaxf(m, pmax[i]);
    red[t] = m; __syncthreads();
    for (int s = 128; s > 0; s >>= 1) {
        if (t < s) red[t] = fmaxf(red[t], red[t + s]);
        __syncthreads();
    }
    if (t == 0) *amaxf = red[0];
}

// L bf16: L[b,i,j] = (i==j) ? rowsum/amax - 1 : -R/amax
__global__ void k_buildL(const float* __restrict__ R, const float* __restrict__ rowsum,
                         const float* __restrict__ amaxf, unsigned short* __restrict__ Lb) {
    int id = blockIdx.x * 256 + threadIdx.x;     // 4.19M threads, 2 elems each
    float inv = 1.0f / (*amaxf);
    size_t e = (size_t)id * 2;
    size_t bi = e >> 9;
    int i = (int)(bi & 511);
    int j0 = (int)(e & 511);
    float2 rv = *(const float2*)(R + e);
    float v0 = (i == j0)     ? (rowsum[bi] * inv - 1.0f) : (-rv.x * inv);
    float v1 = (i == j0 + 1) ? (rowsum[bi] * inv - 1.0f) : (-rv.y * inv);
    u16x2 o; o[0] = f2bf(v0); o[1] = f2bf(v1);
    *(u16x2*)(Lb + e) = o;
}

__global__ void k_F0(const float* __restrict__ X, const float* __restrict__ Wi,
                     const float* __restrict__ bi_, float* __restrict__ F0) {
    int id = blockIdx.x * 256 + threadIdx.x;     // 16384*384
    int row = id / 384, c = id % 384;
    F0[id] = X[row * 3] * Wi[c] + X[row * 3 + 1] * Wi[384 + c] + X[row * 3 + 2] * Wi[768 + c] + bi_[c];
}

// WgT[combo][n][k] = Wg{kp}[(part*384+k)*128 + n], combo = kp*3+part  (bf16)
__global__ void k_prepW(const float* __restrict__ Wg1, const float* __restrict__ Wg2,
                        const float* __restrict__ Wg3, unsigned short* __restrict__ WgT) {
    int id = blockIdx.x * 256 + threadIdx.x;     // 9*128*384 = 442368
    if (id >= 442368) return;
    int combo = id / 49152, rem = id % 49152;
    int n = rem / 384, k = rem % 384;
    int kp = combo / 3, part = combo % 3;
    const float* W = (kp == 0) ? Wg1 : (kp == 1 ? Wg2 : Wg3);
    WgT[id] = f2bf(W[(part * 384 + k) * 128 + n]);
}

__global__ void k_bcat(const float* __restrict__ bg1, const float* __restrict__ bg2,
                       const float* __restrict__ bg3, float* __restrict__ bcat) {
    int c = threadIdx.x;   // 384
    bcat[c] = (c < 128) ? bg1[c] : (c < 256 ? bg2[c - 128] : bg3[c - 256]);
}

// ---------------- MFMA GEMM kernels ----------------
// 128x128 block tile, 256 thr = 4 waves (2x2), each wave 64x64 via 4x4 frags of 16x16x32
// LDS: As/Bs fragment-row-major [128 rows][stride 40 bf16]

#define AST 40

// Y GEMM: pow(F0,kp+1)[16384x384] @ WgT-slice -> Y0/Y1 fp32 or Y2T bf16
__global__ __launch_bounds__(256) void k_ygemm(
    const float* __restrict__ F0, const unsigned short* __restrict__ WgT,
    float* __restrict__ Y0, float* __restrict__ Y1, unsigned short* __restrict__ Y2T)
{
    __shared__ unsigned short As[128 * AST];
    __shared__ unsigned short Bs[128 * AST];
    const int t = threadIdx.x;
    const int tileM = blockIdx.x;        // 0..127
    const int combo = blockIdx.y;        // 0..8
    const int kp = combo / 3, part = combo % 3;

    const int wave = t >> 6, lane = t & 63;
    const int wm = wave >> 1, wn = wave & 1;
    const int quad = lane >> 4, l16 = lane & 15;

    const float* Abase = F0 + (size_t)tileM * 128 * 384;
    const unsigned short* Bbase = WgT + (size_t)combo * 128 * 384;

    const int r0 = t >> 2, p0 = (t & 3) * 8;            // chunk 0: rows 0..63
    const int r1 = r0 + 64;                              // chunk 1: rows 64..127

    f32x4 acc[4][4];
#pragma unroll
    for (int i = 0; i < 4; i++)
#pragma unroll
        for (int n = 0; n < 4; n++) acc[i][n] = (f32x4){0.f, 0.f, 0.f, 0.f};

    float4 a0lo, a0hi, a1lo, a1hi;
    u16x8 b0, b1;
    // prefetch step 0
    {
        const float* p = Abase + r0 * 384 + p0;
        a0lo = *(const float4*)p; a0hi = *(const float4*)(p + 4);
        const float* q = Abase + r1 * 384 + p0;
        a1lo = *(const float4*)q; a1hi = *(const float4*)(q + 4);
        b0 = *(const u16x8*)(Bbase + r0 * 384 + p0);
        b1 = *(const u16x8*)(Bbase + r1 * 384 + p0);
    }

    for (int s = 0; s < 12; s++) {
        if (s > 0) __syncthreads();
        // store staged regs -> LDS (apply power + cvt for A)
        {
            float va[8] = {a0lo.x, a0lo.y, a0lo.z, a0lo.w, a0hi.x, a0hi.y, a0hi.z, a0hi.w};
            float vb[8] = {a1lo.x, a1lo.y, a1lo.z, a1lo.w, a1hi.x, a1hi.y, a1hi.z, a1hi.w};
            u16x8 oa, ob;
#pragma unroll
            for (int j = 0; j < 8; j++) {
                float x = va[j];
                float pxa = (kp == 0) ? x : (kp == 1 ? x * x : x * x * x);
                oa[j] = f2bf(pxa);
                float y = vb[j];
                float pxb = (kp == 0) ? y : (kp == 1 ? y * y : y * y * y);
                ob[j] = f2bf(pxb);
            }
            *(u16x8*)(As + r0 * AST + p0) = oa;
            *(u16x8*)(As + r1 * AST + p0) = ob;
            *(u16x8*)(Bs + r0 * AST + p0) = b0;
            *(u16x8*)(Bs + r1 * AST + p0) = b1;
        }
        __syncthreads();
        if (s < 11) {
            int kB = (s + 1) * 32;
            const float* p = Abase + r0 * 384 + kB + p0;
            a0lo = *(const float4*)p; a0hi = *(const float4*)(p + 4);
            const float* q = Abase + r1 * 384 + kB + p0;
            a1lo = *(const float4*)q; a1hi = *(const float4*)(q + 4);
            b0 = *(const u16x8*)(Bbase + r0 * 384 + kB + p0);
            b1 = *(const u16x8*)(Bbase + r1 * 384 + kB + p0);
        }
        bf16x8 af[4], bfr[4];
#pragma unroll
        for (int i = 0; i < 4; i++)
            af[i] = *(const bf16x8*)(As + (wm * 64 + i * 16 + l16) * AST + quad * 8);
#pragma unroll
        for (int n = 0; n < 4; n++)
            bfr[n] = *(const bf16x8*)(Bs + (wn * 64 + n * 16 + l16) * AST + quad * 8);
#pragma unroll
        for (int i = 0; i < 4; i++)
#pragma unroll
            for (int n = 0; n < 4; n++)
                acc[i][n] = __builtin_amdgcn_mfma_f32_16x16x32_bf16(af[i], bfr[n], acc[i][n], 0, 0, 0);
    }

    // epilogue
    if (part < 2) {
        float* Y = (part == 0) ? Y0 : Y1;
#pragma unroll
        for (int i = 0; i < 4; i++) {
            int row = tileM * 128 + wm * 64 + i * 16 + quad * 4;
#pragma unroll
            for (int n = 0; n < 4; n++) {
                int col = kp * 128 + wn * 64 + n * 16 + l16;
                float* p = Y + (size_t)row * 384 + col;
#pragma unroll
                for (int r = 0; r < 4; r++) p[(size_t)r * 384] = acc[i][n][r];
            }
        }
    } else {
#pragma unroll
        for (int i = 0; i < 4; i++) {
            int grow = tileM * 128 + wm * 64 + i * 16 + quad * 4;
            int b = grow >> 9, node = grow & 511;
#pragma unroll
            for (int n = 0; n < 4; n++) {
                int col = kp * 128 + wn * 64 + n * 16 + l16;
                u16x4 o;
#pragma unroll
                for (int r = 0; r < 4; r++) o[r] = f2bf(acc[i][n][r]);
                *(u16x4*)(Y2T + ((size_t)b * 384 + col) * 512 + node) = o;
            }
        }
    }
}

// L GEMM: per batch C = Cinit + L@B ; MODE 1 -> ZT bf16 ; MODE 2 -> F1 fused epilogue
template <int MODE>
__global__ __launch_bounds__(256) void k_lgemm(
    const unsigned short* __restrict__ Lb,   // [32][512][512] bf16
    const unsigned short* __restrict__ BT,   // [32][384][512] bf16
    const float* __restrict__ Cinit,         // [16384][384]
    unsigned short* __restrict__ ZT,         // MODE1 out [32][384][512]
    float* __restrict__ F1,                  // MODE2 out (in place over F0)
    const float* __restrict__ bcat)
{
    __shared__ unsigned short As[128 * AST];
    __shared__ unsigned short Bs[128 * AST];
    const int t = threadIdx.x;
    const int tileM = blockIdx.x;   // 0..3
    const int tileN = blockIdx.y;   // 0..2
    const int b = blockIdx.z;       // 0..31

    const int wave = t >> 6, lane = t & 63;
    const int wm = wave >> 1, wn = wave & 1;
    const int quad = lane >> 4, l16 = lane & 15;

    const unsigned short* Abase = Lb + (size_t)b * 512 * 512 + (size_t)tileM * 128 * 512;
    const unsigned short* Bbase = BT + (size_t)b * 384 * 512 + (size_t)tileN * 128 * 512;

    const int r0 = t >> 2, p0 = (t & 3) * 8;
    const int r1 = r0 + 64;

    f32x4 acc[4][4];
#pragma unroll
    for (int i = 0; i < 4; i++)
#pragma unroll
        for (int n = 0; n < 4; n++) acc[i][n] = (f32x4){0.f, 0.f, 0.f, 0.f};

    u16x8 a0, a1, b0, b1;
    a0 = *(const u16x8*)(Abase + (size_t)r0 * 512 + p0);
    a1 = *(const u16x8*)(Abase + (size_t)r1 * 512 + p0);
    b0 = *(const u16x8*)(Bbase + (size_t)r0 * 512 + p0);
    b1 = *(const u16x8*)(Bbase + (size_t)r1 * 512 + p0);

    for (int s = 0; s < 16; s++) {
        if (s > 0) __syncthreads();
        *(u16x8*)(As + r0 * AST + p0) = a0;
        *(u16x8*)(As + r1 * AST + p0) = a1;
        *(u16x8*)(Bs + r0 * AST + p0) = b0;
        *(u16x8*)(Bs + r1 * AST + p0) = b1;
        __syncthreads();
        if (s < 15) {
            int kB = (s + 1) * 32;
            a0 = *(const u16x8*)(Abase + (size_t)r0 * 512 + kB + p0);
            a1 = *(const u16x8*)(Abase + (size_t)r1 * 512 + kB + p0);
            b0 = *(const u16x8*)(Bbase + (size_t)r0 * 512 + kB + p0);
            b1 = *(const u16x8*)(Bbase + (size_t)r1 * 512 + kB + p0);
        }
        bf16x8 af[4], bfr[4];
#pragma unroll
        for (int i = 0; i < 4; i++)
            af[i] = *(const bf16x8*)(As + (wm * 64 + i * 16 + l16) * AST + quad * 8);
#pragma unroll
        for (int n = 0; n < 4; n++)
            bfr[n] = *(const bf16x8*)(Bs + (wn * 64 + n * 16 + l16) * AST + quad * 8);
#pragma unroll
        for (int i = 0; i < 4; i++)
#pragma unroll
            for (int n = 0; n < 4; n++)
                acc[i][n] = __builtin_amdgcn_mfma_f32_16x16x32_bf16(af[i], bfr[n], acc[i][n], 0, 0, 0);
    }

#pragma unroll
    for (int i = 0; i < 4; i++) {
        int node = tileM * 128 + wm * 64 + i * 16 + quad * 4;
        size_t grow = (size_t)b * 512 + node;
#pragma unroll
        for (int n = 0; n < 4; n++) {
            int gcol = tileN * 128 + wn * 64 + n * 16 + l16;
            if (MODE == 1) {
                u16x4 o;
#pragma unroll
                for (int r = 0; r < 4; r++) {
                    float c = Cinit[(grow + r) * 384 + gcol] + acc[i][n][r];
                    o[r] = f2bf(c);
                }
                *(u16x4*)(ZT + ((size_t)b * 384 + gcol) * 512 + node) = o;
            } else {
                float bb = bcat[gcol];
#pragma unroll
                for (int r = 0; r < 4; r++) {
                    size_t idx = (grow + r) * 384 + gcol;
                    float c = Cinit[idx] + acc[i][n][r] + bb;
                    float v = LEAKY(c);
                    F1[idx] = v + F1[idx];   // residual: F1 buffer holds F0
                }
            }
        }
    }
}

// F GEMM: F1[16384x384] fp32 (cvt on the fly) @ WFsT bf16 -> leaky -> out rows 1..512
__global__ __launch_bounds__(256) void k_fgemm(
    const float* __restrict__ F1, const unsigned short* __restrict__ WFsT,
    const float* __restrict__ beff, float* __restrict__ out)
{
    __shared__ unsigned short As[128 * AST];
    __shared__ unsigned short Bs[128 * AST];
    const int t = threadIdx.x;
    const int tileM = blockIdx.x;   // 0..127

    const int wave = t >> 6, lane = t & 63;
    const int wm = wave >> 1, wn = wave & 1;
    const int quad = lane >> 4, l16 = lane & 15;

    const float* Abase = F1 + (size_t)tileM * 128 * 384;
    const int r0 = t >> 2, p0 = (t & 3) * 8;
    const int r1 = r0 + 64;

    f32x4 acc[4][4];
#pragma unroll
    for (int i = 0; i < 4; i++)
#pragma unroll
        for (int n = 0; n < 4; n++) acc[i][n] = (f32x4){0.f, 0.f, 0.f, 0.f};

    float4 a0lo, a0hi, a1lo, a1hi;
    u16x8 b0, b1;
    {
        const float* p = Abase + r0 * 384 + p0;
        a0lo = *(const float4*)p; a0hi = *(const float4*)(p + 4);
        const float* q = Abase + r1 * 384 + p0;
        a1lo = *(const float4*)q; a1hi = *(const float4*)(q + 4);
        b0 = *(const u16x8*)(WFsT + r0 * 384 + p0);
        b1 = *(const u16x8*)(WFsT + r1 * 384 + p0);
    }

    for (int s = 0; s < 12; s++) {
        if (s > 0) __syncthreads();
        {
            float va[8] = {a0lo.x, a0lo.y, a0lo.z, a0lo.w, a0hi.x, a0hi.y, a0hi.z, a0hi.w};
            float vb[8] = {a1lo.x, a1lo.y, a1lo.z, a1lo.w, a1hi.x, a1hi.y, a1hi.z, a1hi.w};
            u16x8 oa, ob;
#pragma unroll
            for (int j = 0; j < 8; j++) { oa[j] = f2bf(va[j]); ob[j] = f2bf(vb[j]); }
            *(u16x8*)(As + r0 * AST + p0) = oa;
            *(u16x8*)(As + r1 * AST + p0) = ob;
            *(u16x8*)(Bs + r0 * AST + p0) = b0;
            *(u16x8*)(Bs + r1 * AST + p0) = b1;
        }
        __syncthreads();
        if (s < 11) {
            int kB = (s + 1) * 32;
            const float* p = Abase + r0 * 384 + kB + p0;
            a0lo = *(const float4*)p; a0hi = *(const float4*)(p + 4);
            const float* q = Abase + r1 * 384 + kB + p0;
            a1lo = *(const float4*)q; a1hi = *(const float4*)(q + 4);
            b0 = *(const u16x8*)(WFsT + r0 * 384 + kB + p0);
            b1 = *(const u16x8*)(WFsT + r1 * 384 + kB + p0);
        }
        bf16x8 af[4], bfr[4];
#pragma unroll
        for (int i = 0; i < 4; i++)
            af[i] = *(const bf16x8*)(As + (wm * 64 + i * 16 + l16) * AST + quad * 8);
#pragma unroll
        for (int n = 0; n < 4; n++)
            bfr[n] = *(const bf16x8*)(Bs + (wn * 64 + n * 16 + l16) * AST + quad * 8);
#pragma unroll
        for (int i = 0; i < 4; i++)
#pragma unroll
            for (int n = 0; n < 4; n++)
                acc[i][n] = __builtin_amdgcn_mfma_f32_16x16x32_bf16(af[i], bfr[n], acc[i][n], 0, 0, 0);
    }

#pragma unroll
    for (int i = 0; i < 4; i++) {
        int grow = tileM * 128 + wm * 64 + i * 16 + quad * 4;
        int b = grow >> 9, node = grow & 511;
#pragma unroll
        for (int n = 0; n < 4; n++) {
            int col = wn * 64 + n * 16 + l16;
            float bb = beff[col];
#pragma unroll
            for (int r = 0; r < 4; r++) {
                float x = acc[i][n][r] + bb;
                out[(size_t)b * 65664 + (size_t)(node + r + 1) * 128 + col] = LEAKY(x);
            }
        }
    }
}

// ---------------- BN / epilogue ----------------

__global__ __launch_bounds__(384) void k_bnred(const float* __restrict__ F1,
                                               float* __restrict__ sum1, float* __restrict__ sum2) {
    int c = threadIdx.x;          // 0..383
    int r0 = blockIdx.x * 128;    // 128 blocks
    float s1 = 0.f, s2 = 0.f;
    for (int r = 0; r < 128; r++) {
        float v = F1[(size_t)(r0 + r) * 384 + c];
        s1 += v; s2 += v * v;
    }
    atomicAdd(&sum1[c], s1);
    atomicAdd(&sum2[c], s2);
}

__global__ void k_bnfin(const float* __restrict__ sum1, const float* __restrict__ sum2,
                        const float* __restrict__ gamma, const float* __restrict__ beta,
                        float* __restrict__ s, float* __restrict__ tt) {
    int c = threadIdx.x;   // 384
    float mu = sum1[c] * (1.f / 16384.f);
    float var = sum2[c] * (1.f / 16384.f) - mu * mu;
    float sc = gamma[c] / sqrtf(var + 1e-5f);
    s[c] = sc;
    tt[c] = beta[c] - mu * sc;
}

// WFsT[n][k] = W_F[k][n] * s[k]  (bf16)
__global__ void k_fold(const float* __restrict__ WF, const float* __restrict__ s,
                       unsigned short* __restrict__ WFsT) {
    int id = blockIdx.x * 256 + threadIdx.x;   // 49152
    int n = id / 384, k = id % 384;
    WFsT[id] = f2bf(WF[k * 128 + n] * s[k]);
}

__global__ void k_beff(const float* __restrict__ WF, const float* __restrict__ tt,
                       const float* __restrict__ bF, float* __restrict__ beff) {
    int o = threadIdx.x;   // 128
    float acc = bF[o];
    for (int c = 0; c < 384; c++) acc += tt[c] * WF[c * 128 + o];
    beff[o] = acc;
}

__global__ void k_depot(const float* __restrict__ depot, const float* __restrict__ Wd,
                        const float* __restrict__ bd, float* __restrict__ out) {
    int id = blockIdx.x * 256 + threadIdx.x;   // 4096
    int b = id >> 7, o = id & 127;
    out[(size_t)b * 65664 + o] = depot[b * 2] * Wd[o] + depot[b * 2 + 1] * Wd[128 + o] + bd[o];
}

__global__ void k_mean(const float* __restrict__ out_h, float* __restrict__ out_m) {
    int b = blockIdx.x, o = threadIdx.x;   // 32 x 128
    const float* hb = out_h + (size_t)b * 65664;
    float s = 0.f;
    for (int r = 0; r < 513; r++) s += hb[r * 128 + o];
    out_m[b * 128 + o] = s * (1.0f / 513.0f);
}

// ---------------- launch ----------------

extern "C" void kernel_launch(void* const* d_in, const int* in_sizes, int n_in,
                              void* d_out, int out_size, void* d_ws, size_t ws_size,
                              hipStream_t stream) {
    const float* loc      = (const float*)d_in[0];
    const float* deadline = (const float*)d_in[1];
    const float* depot    = (const float*)d_in[3];
    const float* W_init   = (const float*)d_in[4];
    const float* b_init   = (const float*)d_in[5];
    const float* W_dep    = (const float*)d_in[6];
    const float* b_dep    = (const float*)d_in[7];
    const float* W_g1     = (const float*)d_in[8];
    const float* b_g1     = (const float*)d_in[9];
    const float* W_g2     = (const float*)d_in[10];
    const float* b_g2     = (const float*)d_in[11];
    const float* W_g3     = (const float*)d_in[12];
    const float* b_g3     = (const float*)d_in[13];
    const float* gamma    = (const float*)d_in[14];
    const float* beta     = (const float*)d_in[15];
    const float* W_F      = (const float*)d_in[16];
    const float* b_F      = (const float*)d_in[17];
    float* out = (float*)d_out;
    float* ws  = (float*)d_ws;

    // workspace layout (float offsets, all 16B aligned)
    float* X      = ws + 0;         // 49152
    float* dmaxv  = ws + 49152;     // 8
    float* amaxf  = ws + 49160;     // 8
    float* rowsum = ws + 49168;     // 16384
    float* pmax   = ws + 65552;     // 4096
    float* bn1    = ws + 69648;     // 384
    float* bn2    = ws + 70032;     // 384
    float* sS     = ws + 70416;     // 384
    float* sT     = ws + 70800;     // 384
    float* bcat   = ws + 71184;     // 384
    float* beff   = ws + 71568;     // 128
    unsigned short* WgT  = (unsigned short*)(ws + 71696);    // 442368 bf16
    unsigned short* WFsT = (unsigned short*)(ws + 292880);   // 49152 bf16
    float* Y0     = ws + 317456;    // 8388608 (R fp32 reused as Y0)
    float* R      = Y0;
    float* F0     = ws + 8706064;   // 6291456 (F1 in place)
    float* Y1     = ws + 14997520;  // 6291456
    unsigned short* Lb  = (unsigned short*)(ws + 21288976);  // 8388608 bf16
    unsigned short* Y2T = (unsigned short*)(ws + 25483280);  // 6291456 bf16
    unsigned short* ZT  = (unsigned short*)(ws + 28629008);  // 6291456 bf16
    // total 31.77M floats ~= 127 MB

    hipMemsetAsync(bn1, 0, 2 * 384 * sizeof(float), stream);

    k_dmax<<<1, 256, 0, stream>>>(deadline, dmaxv);
    k_buildX<<<64, 256, 0, stream>>>(loc, deadline, dmaxv, X);
    k_buildR<<<4096, 256, 0, stream>>>(X, R, rowsum, pmax);
    k_amax<<<1, 256, 0, stream>>>(pmax, amaxf);
    k_buildL<<<16384, 256, 0, stream>>>(R, rowsum, amaxf, Lb);
    k_F0<<<24576, 256, 0, stream>>>(X, W_init, b_init, F0);
    k_prepW<<<1728, 256, 0, stream>>>(W_g1, W_g2, W_g3, WgT);
    k_bcat<<<1, 384, 0, stream>>>(b_g1, b_g2, b_g3, bcat);

    dim3 yg(128, 9);
    k_ygemm<<<yg, 256, 0, stream>>>(F0, WgT, Y0, Y1, Y2T);

    dim3 lg(4, 3, 32);
    k_lgemm<1><<<lg, 256, 0, stream>>>(Lb, Y2T, Y1, ZT, nullptr, bcat);  // Z = Y1 + L@Y2 -> ZT
    k_lgemm<2><<<lg, 256, 0, stream>>>(Lb, ZT, Y0, nullptr, F0, bcat);   // F1 = leaky(Y0+L@Z+b)+F0

    k_bnred<<<128, 384, 0, stream>>>(F0, bn1, bn2);
    k_bnfin<<<1, 384, 0, stream>>>(bn1, bn2, gamma, beta, sS, sT);
    k_fold<<<192, 256, 0, stream>>>(W_F, sS, WFsT);
    k_beff<<<1, 128, 0, stream>>>(W_F, sT, b_F, beff);

    k_fgemm<<<128, 256, 0, stream>>>(F0, WFsT, beff, out);
    k_depot<<<16, 256, 0, stream>>>(depot, W_dep, b_dep, out);
    k_mean<<<32, 128, 0, stream>>>(out, out + 2101248);
}

// Round 3
// 266.394 us; speedup vs baseline: 2.9693x; 1.1700x over previous
//
#include <hip/hip_runtime.h>

#define LEAKY(x) ((x) > 0.0f ? (x) : 0.01f * (x))

typedef __attribute__((ext_vector_type(8))) short bf16x8;      // MFMA A/B frag
typedef __attribute__((ext_vector_type(4))) float f32x4;       // MFMA C/D frag
typedef __attribute__((ext_vector_type(4))) unsigned short u16x4;

__device__ __forceinline__ unsigned short f2bf(float f) {
    unsigned int u = __float_as_uint(f);
    unsigned int r = (u + 0x7fffu + ((u >> 16) & 1u)) >> 16;   // RNE
    return (unsigned short)r;
}
__device__ __forceinline__ float bf2f(unsigned short u) {
    return __uint_as_float(((unsigned int)u) << 16);
}

// async global->LDS, 16B per lane; LDS dest = wave-uniform base + lane*16
__device__ __forceinline__ void dma16(const unsigned short* g, unsigned short* l) {
    __builtin_amdgcn_global_load_lds(
        (const __attribute__((address_space(1))) void*)g,
        (__attribute__((address_space(3))) void*)l, 16, 0, 0);
}

// ---------------- small builds ----------------

__global__ void k_dmax(const float* __restrict__ deadline, float* __restrict__ dmax) {
    __shared__ float red[256];
    int t = threadIdx.x;
    float m = -1e30f;
    for (int i = t; i < 16384; i += 256) m = fmaxf(m, deadline[i]);
    red[t] = m; __syncthreads();
    for (int s = 128; s > 0; s >>= 1) {
        if (t < s) red[t] = fmaxf(red[t], red[t + s]);
        __syncthreads();
    }
    if (t == 0) *dmax = red[0];
}

// one wave per (b,i) row; reads loc/deadline directly
__global__ __launch_bounds__(256) void k_buildR(const float* __restrict__ loc,
                                                const float* __restrict__ deadline,
                                                const float* __restrict__ dmaxv,
                                                float* __restrict__ R,
                                                float* __restrict__ rowsum, float* __restrict__ pmax) {
    int blk = blockIdx.x;                       // 0..4095
    int wave = threadIdx.x >> 6, lane = threadIdx.x & 63;
    int bi = blk * 4 + wave;                    // b*512 + i
    int b = bi >> 9, i = bi & 511;
    float invd = 1.0f / (*dmaxv);
    const float* lb = loc + b * 1024;
    const float* db = deadline + b * 512;
    float xi = lb[i * 2], yi = lb[i * 2 + 1], zi = db[i] * invd;
    float lsum = 0.f, lmax = 0.f;
    float* Rrow = R + (size_t)bi * 512;
    for (int j = lane; j < 512; j += 64) {
        float d0 = xi - lb[j * 2], d1 = yi - lb[j * 2 + 1], d2 = zi - db[j] * invd;
        float dd = d0 * d0 + d1 * d1 + d2 * d2;
        float r = (j == i) ? 0.f : rsqrtf(dd);
        Rrow[j] = r;
        lsum += r; lmax = fmaxf(lmax, r);
    }
    for (int off = 32; off > 0; off >>= 1) {
        lsum += __shfl_down(lsum, off);
        lmax = fmaxf(lmax, __shfl_down(lmax, off));
    }
    __shared__ float smax[4];
    if (lane == 0) { rowsum[bi] = lsum; smax[wave] = lmax; }
    __syncthreads();
    if (threadIdx.x == 0) pmax[blk] = fmaxf(fmaxf(smax[0], smax[1]), fmaxf(smax[2], smax[3]));
}

__global__ void k_amax(const float* __restrict__ pmax, float* __restrict__ amaxf) {
    __shared__ float red[256];
    int t = threadIdx.x;
    float m = 0.f;
    for (int i = t; i < 4096; i += 256) m = fmaxf(m, pmax[i]);
    red[t] = m; __syncthreads();
    for (int s = 128; s > 0; s >>= 1) {
        if (t < s) red[t] = fmaxf(red[t], red[t + s]);
        __syncthreads();
    }
    if (t == 0) *amaxf = red[0];
}

// L bf16 (symmetric): L[b,i,j] = (i==j) ? rowsum/amax - 1 : -R/amax
__global__ void k_buildL(const float* __restrict__ R, const float* __restrict__ rowsum,
                         const float* __restrict__ amaxf, unsigned short* __restrict__ Lb) {
    int id = blockIdx.x * 256 + threadIdx.x;     // 2,097,152 threads * 4 elems
    float inv = 1.0f / (*amaxf);
    size_t e = (size_t)id * 4;
    size_t bi = e >> 9;
    int i = (int)(bi & 511);
    int j0 = (int)(e & 511);
    float4 rv = *(const float4*)(R + e);
    float diag = rowsum[bi] * inv - 1.0f;
    u16x4 o;
    o[0] = f2bf(i == j0     ? diag : -rv.x * inv);
    o[1] = f2bf(i == j0 + 1 ? diag : -rv.y * inv);
    o[2] = f2bf(i == j0 + 2 ? diag : -rv.z * inv);
    o[3] = f2bf(i == j0 + 3 ? diag : -rv.w * inv);
    *(u16x4*)(Lb + e) = o;
}

// F0 powers, bf16 row-major [16384][384] x3
__global__ void k_F0pow(const float* __restrict__ loc, const float* __restrict__ deadline,
                        const float* __restrict__ dmaxv,
                        const float* __restrict__ Wi, const float* __restrict__ bi_,
                        unsigned short* __restrict__ P1, unsigned short* __restrict__ P2,
                        unsigned short* __restrict__ P3) {
    int id = blockIdx.x * 256 + threadIdx.x;     // 6,291,456
    int row = id / 384, c = id % 384;
    float x0 = loc[row * 2], x1 = loc[row * 2 + 1], x2 = deadline[row] / (*dmaxv);
    float f = x0 * Wi[c] + x1 * Wi[384 + c] + x2 * Wi[768 + c] + bi_[c];
    P1[id] = f2bf(f);
    P2[id] = f2bf(f * f);
    P3[id] = f2bf(f * f * f);
}

// WgT[combo][n][k] = Wg{kp}[(part*384+k)*128 + n], combo = kp*3+part  (bf16)
__global__ void k_prepW(const float* __restrict__ Wg1, const float* __restrict__ Wg2,
                        const float* __restrict__ Wg3, unsigned short* __restrict__ WgT) {
    int id = blockIdx.x * 256 + threadIdx.x;     // 442368 exact
    int combo = id / 49152, rem = id % 49152;
    int n = rem / 384, k = rem % 384;
    int kp = combo / 3, part = combo % 3;
    const float* W = (kp == 0) ? Wg1 : (kp == 1 ? Wg2 : Wg3);
    WgT[id] = f2bf(W[(part * 384 + k) * 128 + n]);
}

// ---------------- shared MFMA K-phase ----------------
// tile 128(m) x 128(n), 4 waves 2x2, each wave 64x64 = 4x4 frags of 16x16x32.
// LDS stride 32 u16 (64B rows) matches global_load_lds lane mapping exactly.

__device__ __forceinline__ void gemm_phase(
    const unsigned short* __restrict__ Ab, int Astr,   // A rows = m-local 0..127
    const unsigned short* __restrict__ Bb, int Bstr,   // B rows = n-local 0..127
    int ksteps,
    unsigned short* AsL, unsigned short* BsL,
    f32x4 (&acc)[4][4], int t)
{
    const int wave = t >> 6, lane = t & 63;
    const int wm = wave >> 1, wn = wave & 1;
    const int quad = lane >> 4, l16 = lane & 15;
    const int lrow = lane >> 2, lkq = (lane & 3) * 8;
    const int c0 = wave, c1 = wave + 4;                 // 16-row chunks per wave
    for (int s = 0; s < ksteps; s++) {
        __syncthreads();
        int k0 = s * 32;
        dma16(Ab + (size_t)(c0 * 16 + lrow) * Astr + k0 + lkq, AsL + c0 * 512);
        dma16(Ab + (size_t)(c1 * 16 + lrow) * Astr + k0 + lkq, AsL + c1 * 512);
        dma16(Bb + (size_t)(c0 * 16 + lrow) * Bstr + k0 + lkq, BsL + c0 * 512);
        dma16(Bb + (size_t)(c1 * 16 + lrow) * Bstr + k0 + lkq, BsL + c1 * 512);
        __syncthreads();
        bf16x8 af[4], bf[4];
#pragma unroll
        for (int i = 0; i < 4; i++)
            af[i] = *(const bf16x8*)(AsL + (wm * 64 + i * 16 + l16) * 32 + quad * 8);
#pragma unroll
        for (int n = 0; n < 4; n++)
            bf[n] = *(const bf16x8*)(BsL + (wn * 64 + n * 16 + l16) * 32 + quad * 8);
#pragma unroll
        for (int i = 0; i < 4; i++)
#pragma unroll
            for (int n = 0; n < 4; n++)
                acc[i][n] = __builtin_amdgcn_mfma_f32_16x16x32_bf16(af[i], bf[n], acc[i][n], 0, 0, 0);
    }
}

// Y2^T[g][node] = sum_k WgT(kp*3+2)[g][k] * P{kp}[node][k]
__global__ __launch_bounds__(256) void k_ygemmT(
    const unsigned short* __restrict__ WgT,
    const unsigned short* __restrict__ P1, const unsigned short* __restrict__ P2,
    const unsigned short* __restrict__ P3, unsigned short* __restrict__ Y2T)
{
    __shared__ unsigned short AsL[4096], BsL[4096];
    const int t = threadIdx.x;
    const int kp = blockIdx.x;      // m-tile over 384 gcols = kp*128
    const int nb = blockIdx.y;      // node tile 0..3
    const int b = blockIdx.z;
    const unsigned short* P = (kp == 0) ? P1 : (kp == 1 ? P2 : P3);
    const unsigned short* Ab = WgT + (size_t)(kp * 3 + 2) * 49152;
    const unsigned short* Bb = P + ((size_t)b * 512 + nb * 128) * 384;
    f32x4 acc[4][4];
#pragma unroll
    for (int i = 0; i < 4; i++)
#pragma unroll
        for (int n = 0; n < 4; n++) acc[i][n] = (f32x4){0.f, 0.f, 0.f, 0.f};
    gemm_phase(Ab, 384, Bb, 384, 12, AsL, BsL, acc, t);

    const int wave = t >> 6, lane = t & 63;
    const int wm = wave >> 1, wn = wave & 1;
    const int quad = lane >> 4, l16 = lane & 15;
#pragma unroll
    for (int i = 0; i < 4; i++)
#pragma unroll
        for (int n = 0; n < 4; n++) {
            int g = kp * 128 + wm * 64 + i * 16 + quad * 4;
            int node = nb * 128 + wn * 64 + n * 16 + l16;
#pragma unroll
            for (int r = 0; r < 4; r++)
                Y2T[((size_t)b * 384 + g + r) * 512 + node] = f2bf(acc[i][n][r]);
        }
}

// Z^T[g][node] = bf16( sum_k Y2T[g][k]*L[node][k] + sum_k WgT(kp*3+1)[g][k]*P{kp}[node][k] )
__global__ __launch_bounds__(256) void k_lg1T(
    const unsigned short* __restrict__ Lb, const unsigned short* __restrict__ Y2T,
    const unsigned short* __restrict__ WgT,
    const unsigned short* __restrict__ P1, const unsigned short* __restrict__ P2,
    const unsigned short* __restrict__ P3, unsigned short* __restrict__ ZT)
{
    __shared__ unsigned short AsL[4096], BsL[4096];
    const int t = threadIdx.x;
    const int kp = blockIdx.x;      // gcol tile
    const int nb = blockIdx.y;      // node tile
    const int b = blockIdx.z;
    const unsigned short* P = (kp == 0) ? P1 : (kp == 1 ? P2 : P3);
    f32x4 acc[4][4];
#pragma unroll
    for (int i = 0; i < 4; i++)
#pragma unroll
        for (int n = 0; n < 4; n++) acc[i][n] = (f32x4){0.f, 0.f, 0.f, 0.f};
    // phase 1: K=512 over nodes (A=Y2T rows, B=L rows)
    gemm_phase(Y2T + (size_t)b * 196608 + (size_t)kp * 128 * 512, 512,
               Lb + (size_t)b * 262144 + (size_t)nb * 128 * 512, 512,
               16, AsL, BsL, acc, t);
    // phase 2: K=384 (A=WgT part1, B=powF0)
    gemm_phase(WgT + (size_t)(kp * 3 + 1) * 49152, 384,
               P + ((size_t)b * 512 + nb * 128) * 384, 384,
               12, AsL, BsL, acc, t);

    const int wave = t >> 6, lane = t & 63;
    const int wm = wave >> 1, wn = wave & 1;
    const int quad = lane >> 4, l16 = lane & 15;
#pragma unroll
    for (int i = 0; i < 4; i++)
#pragma unroll
        for (int n = 0; n < 4; n++) {
            int g = kp * 128 + wm * 64 + i * 16 + quad * 4;
            int node = nb * 128 + wn * 64 + n * 16 + l16;
#pragma unroll
            for (int r = 0; r < 4; r++)
                ZT[((size_t)b * 384 + g + r) * 512 + node] = f2bf(acc[i][n][r]);
        }
}

// F1[node][g] = leaky( sum L[node][k]*ZT[g][k] + sum P{kp}[node][k]*WgT(kp*3)[g][k] + bias ) + F0
// -> F1b bf16 row-major; fused exact BN sums
__global__ __launch_bounds__(256) void k_lg2(
    const unsigned short* __restrict__ Lb, const unsigned short* __restrict__ ZT,
    const unsigned short* __restrict__ WgT,
    const unsigned short* __restrict__ P1, const unsigned short* __restrict__ P2,
    const unsigned short* __restrict__ P3,
    const float* __restrict__ bg1, const float* __restrict__ bg2, const float* __restrict__ bg3,
    unsigned short* __restrict__ F1b, float* __restrict__ bn1, float* __restrict__ bn2)
{
    __shared__ unsigned short AsL[4096], BsL[4096];
    __shared__ float bnS[128], bnQ[128];
    const int t = threadIdx.x;
    const int mb = blockIdx.x;      // node tile 0..3
    const int kp = blockIdx.y;      // gcol tile 0..2
    const int b = blockIdx.z;
    if (t < 128) { bnS[t] = 0.f; bnQ[t] = 0.f; }
    const unsigned short* P = (kp == 0) ? P1 : (kp == 1 ? P2 : P3);
    f32x4 acc[4][4];
#pragma unroll
    for (int i = 0; i < 4; i++)
#pragma unroll
        for (int n = 0; n < 4; n++) acc[i][n] = (f32x4){0.f, 0.f, 0.f, 0.f};
    // phase 1: K=512 (A=L rows, B=ZT rows)
    gemm_phase(Lb + (size_t)b * 262144 + (size_t)mb * 128 * 512, 512,
               ZT + (size_t)b * 196608 + (size_t)kp * 128 * 512, 512,
               16, AsL, BsL, acc, t);
    // phase 2: K=384 (A=powF0 rows, B=WgT part0)
    gemm_phase(P + ((size_t)b * 512 + mb * 128) * 384, 384,
               WgT + (size_t)(kp * 3 + 0) * 49152, 384,
               12, AsL, BsL, acc, t);

    const int wave = t >> 6, lane = t & 63;
    const int wm = wave >> 1, wn = wave & 1;
    const int quad = lane >> 4, l16 = lane & 15;
    const float* bg = (kp == 0) ? bg1 : (kp == 1 ? bg2 : bg3);
    float ls1[4], ls2[4];
#pragma unroll
    for (int n = 0; n < 4; n++) { ls1[n] = 0.f; ls2[n] = 0.f; }
#pragma unroll
    for (int i = 0; i < 4; i++) {
        int rowl = mb * 128 + wm * 64 + i * 16 + quad * 4;
        size_t rowg = (size_t)b * 512 + rowl;
#pragma unroll
        for (int n = 0; n < 4; n++) {
            int colloc = wn * 64 + n * 16 + l16;
            int g = kp * 128 + colloc;
            float bias = bg[colloc];
#pragma unroll
            for (int r = 0; r < 4; r++) {
                size_t idx = (rowg + r) * 384 + g;
                float c = acc[i][n][r] + bias;
                float v = LEAKY(c) + bf2f(P1[idx]);   // residual +F0
                F1b[idx] = f2bf(v);
                ls1[n] += v; ls2[n] += v * v;
            }
        }
    }
#pragma unroll
    for (int n = 0; n < 4; n++) {
        int colloc = wn * 64 + n * 16 + l16;
        atomicAdd(&bnS[colloc], ls1[n]);
        atomicAdd(&bnQ[colloc], ls2[n]);
    }
    __syncthreads();
    if (t < 128) {
        atomicAdd(&bn1[kp * 128 + t], bnS[t]);
        atomicAdd(&bn2[kp * 128 + t], bnQ[t]);
    }
}

// BN finish + effective bias for folded final GEMM
__global__ __launch_bounds__(384) void k_bnfin_beff(
    const float* __restrict__ bn1, const float* __restrict__ bn2,
    const float* __restrict__ gamma, const float* __restrict__ beta,
    const float* __restrict__ WF, const float* __restrict__ bF,
    float* __restrict__ sS, float* __restrict__ beffv)
{
    __shared__ float ttL[384];
    int c = threadIdx.x;
    float mu = bn1[c] * (1.f / 16384.f);
    float var = bn2[c] * (1.f / 16384.f) - mu * mu;
    float sc = gamma[c] / sqrtf(var + 1e-5f);
    sS[c] = sc;
    ttL[c] = beta[c] - mu * sc;
    __syncthreads();
    if (c < 128) {
        float a = bF[c];
        for (int k = 0; k < 384; k++) a += ttL[k] * WF[k * 128 + c];
        beffv[c] = a;
    }
}

// WFsT[n][k] = W_F[k][n] * sS[k]  (bf16)
__global__ void k_fold(const float* __restrict__ WF, const float* __restrict__ sS,
                       unsigned short* __restrict__ WFsT) {
    int id = blockIdx.x * 256 + threadIdx.x;   // 49152
    int n = id / 384, k = id % 384;
    WFsT[id] = f2bf(WF[k * 128 + n] * sS[k]);
}

// out rows 1..512 = leaky(F1b @ WFsT + beff); fused column-sum partials
__global__ __launch_bounds__(256) void k_fgemm(
    const unsigned short* __restrict__ F1b, const unsigned short* __restrict__ WFsT,
    const float* __restrict__ beffv, float* __restrict__ out, float* __restrict__ msum)
{
    __shared__ unsigned short AsL[4096], BsL[4096];
    __shared__ float msS[128];
    const int t = threadIdx.x;
    const int mb = blockIdx.x;      // 0..127 (128 rows each)
    if (t < 128) msS[t] = 0.f;
    f32x4 acc[4][4];
#pragma unroll
    for (int i = 0; i < 4; i++)
#pragma unroll
        for (int n = 0; n < 4; n++) acc[i][n] = (f32x4){0.f, 0.f, 0.f, 0.f};
    gemm_phase(F1b + (size_t)mb * 128 * 384, 384, WFsT, 384, 12, AsL, BsL, acc, t);

    const int wave = t >> 6, lane = t & 63;
    const int wm = wave >> 1, wn = wave & 1;
    const int quad = lane >> 4, l16 = lane & 15;
    const int bloc = mb >> 2;
    float ls[4];
#pragma unroll
    for (int n = 0; n < 4; n++) ls[n] = 0.f;
#pragma unroll
    for (int i = 0; i < 4; i++) {
        int rowg = mb * 128 + wm * 64 + i * 16 + quad * 4;
        int nd = rowg & 511;
#pragma unroll
        for (int n = 0; n < 4; n++) {
            int col = wn * 64 + n * 16 + l16;
            float bb = beffv[col];
#pragma unroll
            for (int r = 0; r < 4; r++) {
                float x = acc[i][n][r] + bb;
                float v = LEAKY(x);
                out[(size_t)bloc * 65664 + (size_t)(nd + r + 1) * 128 + col] = v;
                ls[n] += v;
            }
        }
    }
#pragma unroll
    for (int n = 0; n < 4; n++) atomicAdd(&msS[wn * 64 + n * 16 + l16], ls[n]);
    __syncthreads();
    if (t < 128) atomicAdd(&msum[bloc * 128 + t], msS[t]);
}

// depot row + final means
__global__ void k_meandep(const float* __restrict__ depot, const float* __restrict__ Wd,
                          const float* __restrict__ bd, const float* __restrict__ msum,
                          float* __restrict__ out) {
    int id = blockIdx.x * 256 + threadIdx.x;   // 4096
    int b = id >> 7, o = id & 127;
    float dep = depot[b * 2] * Wd[o] + depot[b * 2 + 1] * Wd[128 + o] + bd[o];
    out[(size_t)b * 65664 + o] = dep;
    out[2101248 + id] = (msum[id] + dep) * (1.0f / 513.0f);
}

// ---------------- launch ----------------

extern "C" void kernel_launch(void* const* d_in, const int* in_sizes, int n_in,
                              void* d_out, int out_size, void* d_ws, size_t ws_size,
                              hipStream_t stream) {
    const float* loc      = (const float*)d_in[0];
    const float* deadline = (const float*)d_in[1];
    const float* depot    = (const float*)d_in[3];
    const float* W_init   = (const float*)d_in[4];
    const float* b_init   = (const float*)d_in[5];
    const float* W_dep    = (const float*)d_in[6];
    const float* b_dep    = (const float*)d_in[7];
    const float* W_g1     = (const float*)d_in[8];
    const float* b_g1     = (const float*)d_in[9];
    const float* W_g2     = (const float*)d_in[10];
    const float* b_g2     = (const float*)d_in[11];
    const float* W_g3     = (const float*)d_in[12];
    const float* b_g3     = (const float*)d_in[13];
    const float* gamma    = (const float*)d_in[14];
    const float* beta     = (const float*)d_in[15];
    const float* W_F      = (const float*)d_in[16];
    const float* b_F      = (const float*)d_in[17];
    float* out = (float*)d_out;
    float* ws  = (float*)d_ws;

    // workspace (float offsets, all 16B aligned); total ~31.73M floats ~= 127 MB
    float* dmaxv  = ws + 0;         // 4
    float* amaxf  = ws + 4;         // 4
    float* bn1    = ws + 8;         // 384
    float* bn2    = ws + 392;       // 384
    float* msum   = ws + 776;       // 4096
    float* rowsum = ws + 4872;      // 16384
    float* pmax   = ws + 21256;     // 4096
    float* sS     = ws + 25352;     // 384
    float* beffv  = ws + 25736;     // 128
    float* R      = ws + 25864;     // 8388608
    unsigned short* Lb   = (unsigned short*)(ws + 8414472);   // 8388608 u16
    unsigned short* P1   = (unsigned short*)(ws + 12608776);  // 6291456 u16
    unsigned short* P2   = (unsigned short*)(ws + 15754504);
    unsigned short* P3   = (unsigned short*)(ws + 18900232);
    unsigned short* WgT  = (unsigned short*)(ws + 22045960);  // 442368 u16
    unsigned short* WFsT = (unsigned short*)(ws + 22267144);  // 49152 u16
    unsigned short* Y2T  = (unsigned short*)(ws + 22291720);  // 6291456 u16
    unsigned short* ZT   = (unsigned short*)(ws + 25437448);
    unsigned short* F1b  = (unsigned short*)(ws + 28583176);

    hipMemsetAsync(bn1, 0, (384 + 384 + 4096) * sizeof(float), stream);

    k_dmax<<<1, 256, 0, stream>>>(deadline, dmaxv);
    k_buildR<<<4096, 256, 0, stream>>>(loc, deadline, dmaxv, R, rowsum, pmax);
    k_amax<<<1, 256, 0, stream>>>(pmax, amaxf);
    k_buildL<<<8192, 256, 0, stream>>>(R, rowsum, amaxf, Lb);
    k_F0pow<<<24576, 256, 0, stream>>>(loc, deadline, dmaxv, W_init, b_init, P1, P2, P3);
    k_prepW<<<1728, 256, 0, stream>>>(W_g1, W_g2, W_g3, WgT);

    k_ygemmT<<<dim3(3, 4, 32), 256, 0, stream>>>(WgT, P1, P2, P3, Y2T);
    k_lg1T<<<dim3(3, 4, 32), 256, 0, stream>>>(Lb, Y2T, WgT, P1, P2, P3, ZT);
    k_lg2<<<dim3(4, 3, 32), 256, 0, stream>>>(Lb, ZT, WgT, P1, P2, P3,
                                              b_g1, b_g2, b_g3, F1b, bn1, bn2);

    k_bnfin_beff<<<1, 384, 0, stream>>>(bn1, bn2, gamma, beta, W_F, b_F, sS, beffv);
    k_fold<<<192, 256, 0, stream>>>(W_F, sS, WFsT);
    k_fgemm<<<128, 256, 0, stream>>>(F1b, WFsT, beffv, out, msum);
    k_meandep<<<16, 256, 0, stream>>>(depot, W_dep, b_dep, msum, out);
}

// Round 4
// 265.698 us; speedup vs baseline: 2.9771x; 1.0026x over previous
//
#include <hip/hip_runtime.h>

#define LEAKY(x) ((x) > 0.0f ? (x) : 0.01f * (x))

typedef __attribute__((ext_vector_type(8))) short bf16x8;      // MFMA A/B frag
typedef __attribute__((ext_vector_type(4))) float f32x4;       // MFMA C/D frag
typedef __attribute__((ext_vector_type(4))) unsigned short u16x4;

__device__ __forceinline__ unsigned short f2bf(float f) {
    unsigned int u = __float_as_uint(f);
    unsigned int r = (u + 0x7fffu + ((u >> 16) & 1u)) >> 16;   // RNE
    return (unsigned short)r;
}
__device__ __forceinline__ float bf2f(unsigned short u) {
    return __uint_as_float(((unsigned int)u) << 16);
}

// async global->LDS, 16B per lane; LDS dest = wave-uniform base + lane*16
__device__ __forceinline__ void dma16(const unsigned short* g, unsigned short* l) {
    __builtin_amdgcn_global_load_lds(
        (const __attribute__((address_space(1))) void*)g,
        (__attribute__((address_space(3))) void*)l, 16, 0, 0);
}

// ---------------- small builds ----------------

__global__ void k_dmax(const float* __restrict__ deadline, float* __restrict__ dmax) {
    __shared__ float red[256];
    int t = threadIdx.x;
    float m = -1e30f;
    for (int i = t; i < 16384; i += 256) m = fmaxf(m, deadline[i]);
    red[t] = m; __syncthreads();
    for (int s = 128; s > 0; s >>= 1) {
        if (t < s) red[t] = fmaxf(red[t], red[t + s]);
        __syncthreads();
    }
    if (t == 0) *dmax = red[0];
}

// one wave per (b,i) row
__global__ __launch_bounds__(256) void k_buildR(const float* __restrict__ loc,
                                                const float* __restrict__ deadline,
                                                const float* __restrict__ dmaxv,
                                                float* __restrict__ R,
                                                float* __restrict__ rowsum, float* __restrict__ pmax) {
    int blk = blockIdx.x;                       // 0..4095
    int wave = threadIdx.x >> 6, lane = threadIdx.x & 63;
    int bi = blk * 4 + wave;                    // b*512 + i
    int b = bi >> 9, i = bi & 511;
    float invd = 1.0f / (*dmaxv);
    const float* lb = loc + b * 1024;
    const float* db = deadline + b * 512;
    float xi = lb[i * 2], yi = lb[i * 2 + 1], zi = db[i] * invd;
    float lsum = 0.f, lmax = 0.f;
    float* Rrow = R + (size_t)bi * 512;
    for (int j = lane; j < 512; j += 64) {
        float d0 = xi - lb[j * 2], d1 = yi - lb[j * 2 + 1], d2 = zi - db[j] * invd;
        float dd = d0 * d0 + d1 * d1 + d2 * d2;
        float r = (j == i) ? 0.f : rsqrtf(dd);
        Rrow[j] = r;
        lsum += r; lmax = fmaxf(lmax, r);
    }
    for (int off = 32; off > 0; off >>= 1) {
        lsum += __shfl_down(lsum, off);
        lmax = fmaxf(lmax, __shfl_down(lmax, off));
    }
    __shared__ float smax[4];
    if (lane == 0) { rowsum[bi] = lsum; smax[wave] = lmax; }
    __syncthreads();
    if (threadIdx.x == 0) pmax[blk] = fmaxf(fmaxf(smax[0], smax[1]), fmaxf(smax[2], smax[3]));
}

__global__ void k_amax(const float* __restrict__ pmax, float* __restrict__ amaxf) {
    __shared__ float red[256];
    int t = threadIdx.x;
    float m = 0.f;
    for (int i = t; i < 4096; i += 256) m = fmaxf(m, pmax[i]);
    red[t] = m; __syncthreads();
    for (int s = 128; s > 0; s >>= 1) {
        if (t < s) red[t] = fmaxf(red[t], red[t + s]);
        __syncthreads();
    }
    if (t == 0) *amaxf = red[0];
}

// L bf16 (symmetric): L[b,i,j] = (i==j) ? rowsum/amax - 1 : -R/amax
__global__ void k_buildL(const float* __restrict__ R, const float* __restrict__ rowsum,
                         const float* __restrict__ amaxf, unsigned short* __restrict__ Lb) {
    int id = blockIdx.x * 256 + threadIdx.x;     // 2,097,152 threads * 4 elems
    float inv = 1.0f / (*amaxf);
    size_t e = (size_t)id * 4;
    size_t bi = e >> 9;
    int i = (int)(bi & 511);
    int j0 = (int)(e & 511);
    float4 rv = *(const float4*)(R + e);
    float diag = rowsum[bi] * inv - 1.0f;
    u16x4 o;
    o[0] = f2bf(i == j0     ? diag : -rv.x * inv);
    o[1] = f2bf(i == j0 + 1 ? diag : -rv.y * inv);
    o[2] = f2bf(i == j0 + 2 ? diag : -rv.z * inv);
    o[3] = f2bf(i == j0 + 3 ? diag : -rv.w * inv);
    *(u16x4*)(Lb + e) = o;
}

// F0 powers, bf16 row-major [16384][384] x3, 4 cols per thread
__global__ void k_F0pow(const float* __restrict__ loc, const float* __restrict__ deadline,
                        const float* __restrict__ dmaxv,
                        const float* __restrict__ Wi, const float* __restrict__ bi_,
                        unsigned short* __restrict__ P1, unsigned short* __restrict__ P2,
                        unsigned short* __restrict__ P3) {
    int id = blockIdx.x * 256 + threadIdx.x;     // 1,572,864
    int row = id / 96, c4 = (id % 96) * 4;
    float x0 = loc[row * 2], x1 = loc[row * 2 + 1], x2 = deadline[row] / (*dmaxv);
    float4 w0 = *(const float4*)(Wi + c4);
    float4 w1 = *(const float4*)(Wi + 384 + c4);
    float4 w2 = *(const float4*)(Wi + 768 + c4);
    float4 bb = *(const float4*)(bi_ + c4);
    float f[4] = {x0 * w0.x + x1 * w1.x + x2 * w2.x + bb.x,
                  x0 * w0.y + x1 * w1.y + x2 * w2.y + bb.y,
                  x0 * w0.z + x1 * w1.z + x2 * w2.z + bb.z,
                  x0 * w0.w + x1 * w1.w + x2 * w2.w + bb.w};
    u16x4 o1, o2, o3;
#pragma unroll
    for (int j = 0; j < 4; j++) {
        o1[j] = f2bf(f[j]); o2[j] = f2bf(f[j] * f[j]); o3[j] = f2bf(f[j] * f[j] * f[j]);
    }
    size_t e = (size_t)row * 384 + c4;
    *(u16x4*)(P1 + e) = o1; *(u16x4*)(P2 + e) = o2; *(u16x4*)(P3 + e) = o3;
}

// WgT[combo][n][k] = Wg{kp}[(part*384+k)*128 + n], combo = kp*3+part  (bf16)
__global__ void k_prepW(const float* __restrict__ Wg1, const float* __restrict__ Wg2,
                        const float* __restrict__ Wg3, unsigned short* __restrict__ WgT) {
    int id = blockIdx.x * 256 + threadIdx.x;     // 442368 exact
    int combo = id / 49152, rem = id % 49152;
    int n = rem / 384, k = rem % 384;
    int kp = combo / 3, part = combo % 3;
    const float* W = (kp == 0) ? Wg1 : (kp == 1 ? Wg2 : Wg3);
    WgT[id] = f2bf(W[(part * 384 + k) * 128 + n]);
}

// ---------------- MFMA phases ----------------
// tile 128(m) x 64(n), 4 waves 2x2 -> wave tile 64x32 (4x2 frags of 16x16x32).
// BK=64 per barrier pair: two 32-wide LDS panels (stride 32 u16) staged per sync.
// AsL: 2 panels x 128x32 = 8192 u16 (16 KB); BsL: 2 panels x 64x32 = 4096 u16 (8 KB)

__device__ __forceinline__ void phase128x64(
    const unsigned short* __restrict__ Ab, int Astr,
    const unsigned short* __restrict__ Bb, int Bstr,
    int kiters, unsigned short* AsL, unsigned short* BsL,
    f32x4 (&acc)[4][2], int t)
{
    const int wave = t >> 6, lane = t & 63;
    const int wm = wave >> 1, wn = wave & 1;
    const int quad = lane >> 4, l16 = lane & 15;
    const int lrow = lane >> 2, lkq = (lane & 3) * 8;
    for (int s = 0; s < kiters; s++) {
        __syncthreads();
        int k0 = s * 64;
#pragma unroll
        for (int h = 0; h < 2; h++) {
            const unsigned short* Ah = Ab + k0 + h * 32 + lkq;
            unsigned short* Ap = AsL + h * 4096;
            dma16(Ah + (size_t)(wave * 16 + lrow) * Astr, Ap + wave * 512);
            dma16(Ah + (size_t)((wave + 4) * 16 + lrow) * Astr, Ap + (wave + 4) * 512);
            dma16(Bb + k0 + h * 32 + lkq + (size_t)(wave * 16 + lrow) * Bstr,
                  BsL + h * 2048 + wave * 512);
        }
        __syncthreads();
#pragma unroll
        for (int h = 0; h < 2; h++) {
            bf16x8 af[4], bfr[2];
#pragma unroll
            for (int i = 0; i < 4; i++)
                af[i] = *(const bf16x8*)(AsL + h * 4096 + (wm * 64 + i * 16 + l16) * 32 + quad * 8);
#pragma unroll
            for (int n = 0; n < 2; n++)
                bfr[n] = *(const bf16x8*)(BsL + h * 2048 + (wn * 32 + n * 16 + l16) * 32 + quad * 8);
#pragma unroll
            for (int i = 0; i < 4; i++)
#pragma unroll
                for (int n = 0; n < 2; n++)
                    acc[i][n] = __builtin_amdgcn_mfma_f32_16x16x32_bf16(af[i], bfr[n], acc[i][n], 0, 0, 0);
        }
    }
}

// 64x64 tile, 4 waves 2x2 -> wave tile 32x32 (2x2 frags)
__device__ __forceinline__ void phase64x64(
    const unsigned short* __restrict__ Ab, int Astr,
    const unsigned short* __restrict__ Bb, int Bstr,
    int kiters, unsigned short* AsL, unsigned short* BsL,
    f32x4 (&acc)[2][2], int t)
{
    const int wave = t >> 6, lane = t & 63;
    const int wm = wave >> 1, wn = wave & 1;
    const int quad = lane >> 4, l16 = lane & 15;
    const int lrow = lane >> 2, lkq = (lane & 3) * 8;
    for (int s = 0; s < kiters; s++) {
        __syncthreads();
        int k0 = s * 64;
#pragma unroll
        for (int h = 0; h < 2; h++) {
            dma16(Ab + k0 + h * 32 + lkq + (size_t)(wave * 16 + lrow) * Astr,
                  AsL + h * 2048 + wave * 512);
            dma16(Bb + k0 + h * 32 + lkq + (size_t)(wave * 16 + lrow) * Bstr,
                  BsL + h * 2048 + wave * 512);
        }
        __syncthreads();
#pragma unroll
        for (int h = 0; h < 2; h++) {
            bf16x8 af[2], bfr[2];
#pragma unroll
            for (int i = 0; i < 2; i++)
                af[i] = *(const bf16x8*)(AsL + h * 2048 + (wm * 32 + i * 16 + l16) * 32 + quad * 8);
#pragma unroll
            for (int n = 0; n < 2; n++)
                bfr[n] = *(const bf16x8*)(BsL + h * 2048 + (wn * 32 + n * 16 + l16) * 32 + quad * 8);
#pragma unroll
            for (int i = 0; i < 2; i++)
#pragma unroll
                for (int n = 0; n < 2; n++)
                    acc[i][n] = __builtin_amdgcn_mfma_f32_16x16x32_bf16(af[i], bfr[n], acc[i][n], 0, 0, 0);
        }
    }
}

// Y2^T[g][node] = sum_k WgT(kp*3+2)[g][k] * P{kp}[node][k]
__global__ __launch_bounds__(256) void k_ygemmT(
    const unsigned short* __restrict__ WgT,
    const unsigned short* __restrict__ P1, const unsigned short* __restrict__ P2,
    const unsigned short* __restrict__ P3, unsigned short* __restrict__ Y2T)
{
    __shared__ unsigned short AsL[8192], BsL[4096];
    const int t = threadIdx.x;
    const int kp = blockIdx.x;      // gcol tile of 128
    const int nb = blockIdx.y;      // node tile of 64 (0..7)
    const int b = blockIdx.z;
    const unsigned short* P = (kp == 0) ? P1 : (kp == 1 ? P2 : P3);
    f32x4 acc[4][2];
#pragma unroll
    for (int i = 0; i < 4; i++)
#pragma unroll
        for (int n = 0; n < 2; n++) acc[i][n] = (f32x4){0.f, 0.f, 0.f, 0.f};
    phase128x64(WgT + (size_t)(kp * 3 + 2) * 49152, 384,
                P + ((size_t)b * 512 + nb * 64) * 384, 384, 6, AsL, BsL, acc, t);

    const int wave = t >> 6, lane = t & 63;
    const int wm = wave >> 1, wn = wave & 1;
    const int quad = lane >> 4, l16 = lane & 15;
#pragma unroll
    for (int i = 0; i < 4; i++)
#pragma unroll
        for (int n = 0; n < 2; n++) {
            int g = kp * 128 + wm * 64 + i * 16 + quad * 4;
            int node = nb * 64 + wn * 32 + n * 16 + l16;
#pragma unroll
            for (int r = 0; r < 4; r++)
                Y2T[((size_t)b * 384 + g + r) * 512 + node] = f2bf(acc[i][n][r]);
        }
}

// Z^T[g][node] = bf16( Y2T-row dot L-row + WgT(kp*3+1)-row dot P-row )
__global__ __launch_bounds__(256) void k_lg1T(
    const unsigned short* __restrict__ Lb, const unsigned short* __restrict__ Y2T,
    const unsigned short* __restrict__ WgT,
    const unsigned short* __restrict__ P1, const unsigned short* __restrict__ P2,
    const unsigned short* __restrict__ P3, unsigned short* __restrict__ ZT)
{
    __shared__ unsigned short AsL[8192], BsL[4096];
    const int t = threadIdx.x;
    const int kp = blockIdx.x;      // gcol tile 128
    const int nb = blockIdx.y;      // node tile 64
    const int b = blockIdx.z;
    const unsigned short* P = (kp == 0) ? P1 : (kp == 1 ? P2 : P3);
    f32x4 acc[4][2];
#pragma unroll
    for (int i = 0; i < 4; i++)
#pragma unroll
        for (int n = 0; n < 2; n++) acc[i][n] = (f32x4){0.f, 0.f, 0.f, 0.f};
    phase128x64(Y2T + (size_t)b * 196608 + (size_t)kp * 128 * 512, 512,
                Lb + (size_t)b * 262144 + (size_t)nb * 64 * 512, 512, 8, AsL, BsL, acc, t);
    phase128x64(WgT + (size_t)(kp * 3 + 1) * 49152, 384,
                P + ((size_t)b * 512 + nb * 64) * 384, 384, 6, AsL, BsL, acc, t);

    const int wave = t >> 6, lane = t & 63;
    const int wm = wave >> 1, wn = wave & 1;
    const int quad = lane >> 4, l16 = lane & 15;
#pragma unroll
    for (int i = 0; i < 4; i++)
#pragma unroll
        for (int n = 0; n < 2; n++) {
            int g = kp * 128 + wm * 64 + i * 16 + quad * 4;
            int node = nb * 64 + wn * 32 + n * 16 + l16;
#pragma unroll
            for (int r = 0; r < 4; r++)
                ZT[((size_t)b * 384 + g + r) * 512 + node] = f2bf(acc[i][n][r]);
        }
}

// F1 = leaky(L-row dot ZT-row + P-row dot WgT(kp*3)-row + bias) + F0 ; fused BN sums
__global__ __launch_bounds__(256) void k_lg2(
    const unsigned short* __restrict__ Lb, const unsigned short* __restrict__ ZT,
    const unsigned short* __restrict__ WgT,
    const unsigned short* __restrict__ P1, const unsigned short* __restrict__ P2,
    const unsigned short* __restrict__ P3,
    const float* __restrict__ bg1, const float* __restrict__ bg2, const float* __restrict__ bg3,
    unsigned short* __restrict__ F1b, float* __restrict__ bn1, float* __restrict__ bn2)
{
    __shared__ unsigned short AsL[8192], BsL[4096];
    __shared__ float bnS[64], bnQ[64];
    const int t = threadIdx.x;
    const int mb = blockIdx.x;      // node tile 128 (0..3)
    const int gt = blockIdx.y;      // gcol tile 64 (0..5)
    const int b = blockIdx.z;
    const int kp = gt >> 1;
    if (t < 64) { bnS[t] = 0.f; bnQ[t] = 0.f; }
    const unsigned short* P = (kp == 0) ? P1 : (kp == 1 ? P2 : P3);
    f32x4 acc[4][2];
#pragma unroll
    for (int i = 0; i < 4; i++)
#pragma unroll
        for (int n = 0; n < 2; n++) acc[i][n] = (f32x4){0.f, 0.f, 0.f, 0.f};
    phase128x64(Lb + (size_t)b * 262144 + (size_t)mb * 128 * 512, 512,
                ZT + (size_t)b * 196608 + (size_t)gt * 64 * 512, 512, 8, AsL, BsL, acc, t);
    phase128x64(P + ((size_t)b * 512 + mb * 128) * 384, 384,
                WgT + (size_t)(kp * 3) * 49152 + (size_t)(gt & 1) * 64 * 384, 384, 6, AsL, BsL, acc, t);

    const int wave = t >> 6, lane = t & 63;
    const int wm = wave >> 1, wn = wave & 1;
    const int quad = lane >> 4, l16 = lane & 15;
    const float* bg = (kp == 0) ? bg1 : (kp == 1 ? bg2 : bg3);
    float ls1[2], ls2[2];
#pragma unroll
    for (int n = 0; n < 2; n++) { ls1[n] = 0.f; ls2[n] = 0.f; }
#pragma unroll
    for (int i = 0; i < 4; i++) {
        int rowl = mb * 128 + wm * 64 + i * 16 + quad * 4;
        size_t rowg = (size_t)b * 512 + rowl;
#pragma unroll
        for (int n = 0; n < 2; n++) {
            int nloc = wn * 32 + n * 16 + l16;
            int g = gt * 64 + nloc;
            float bias = bg[(gt & 1) * 64 + nloc];
#pragma unroll
            for (int r = 0; r < 4; r++) {
                size_t idx = (rowg + r) * 384 + g;
                float c = acc[i][n][r] + bias;
                float v = LEAKY(c) + bf2f(P1[idx]);   // residual +F0
                F1b[idx] = f2bf(v);
                ls1[n] += v; ls2[n] += v * v;
            }
        }
    }
#pragma unroll
    for (int n = 0; n < 2; n++) {
        int nloc = wn * 32 + n * 16 + l16;
        atomicAdd(&bnS[nloc], ls1[n]);
        atomicAdd(&bnQ[nloc], ls2[n]);
    }
    __syncthreads();
    if (t < 64) {
        atomicAdd(&bn1[gt * 64 + t], bnS[t]);
        atomicAdd(&bn2[gt * 64 + t], bnQ[t]);
    }
}

// BN finish + effective bias for folded final GEMM
__global__ __launch_bounds__(384) void k_bnfin_beff(
    const float* __restrict__ bn1, const float* __restrict__ bn2,
    const float* __restrict__ gamma, const float* __restrict__ beta,
    const float* __restrict__ WF, const float* __restrict__ bF,
    float* __restrict__ sS, float* __restrict__ beffv)
{
    __shared__ float ttL[384];
    int c = threadIdx.x;
    float mu = bn1[c] * (1.f / 16384.f);
    float var = bn2[c] * (1.f / 16384.f) - mu * mu;
    float sc = gamma[c] / sqrtf(var + 1e-5f);
    sS[c] = sc;
    ttL[c] = beta[c] - mu * sc;
    __syncthreads();
    if (c < 128) {
        float a = bF[c];
        for (int k = 0; k < 384; k++) a += ttL[k] * WF[k * 128 + c];
        beffv[c] = a;
    }
}

// WFsT[n][k] = W_F[k][n] * sS[k]  (bf16)
__global__ void k_fold(const float* __restrict__ WF, const float* __restrict__ sS,
                       unsigned short* __restrict__ WFsT) {
    int id = blockIdx.x * 256 + threadIdx.x;   // 49152
    int n = id / 384, k = id % 384;
    WFsT[id] = f2bf(WF[k * 128 + n] * sS[k]);
}

// out rows 1..512 = leaky(F1b @ WFsT + beff); fused column-sum partials
__global__ __launch_bounds__(256) void k_fgemm(
    const unsigned short* __restrict__ F1b, const unsigned short* __restrict__ WFsT,
    const float* __restrict__ beffv, float* __restrict__ out, float* __restrict__ msum)
{
    __shared__ unsigned short AsL[4096], BsL[4096];
    __shared__ float msS[64];
    const int t = threadIdx.x;
    const int mb = blockIdx.x;      // 0..255 (64 rows each)
    const int nt = blockIdx.y;      // 0..1  (64 cols each)
    if (t < 64) msS[t] = 0.f;
    f32x4 acc[2][2];
#pragma unroll
    for (int i = 0; i < 2; i++)
#pragma unroll
        for (int n = 0; n < 2; n++) acc[i][n] = (f32x4){0.f, 0.f, 0.f, 0.f};
    phase64x64(F1b + (size_t)mb * 64 * 384, 384,
               WFsT + (size_t)nt * 64 * 384, 384, 6, AsL, BsL, acc, t);

    const int wave = t >> 6, lane = t & 63;
    const int wm = wave >> 1, wn = wave & 1;
    const int quad = lane >> 4, l16 = lane & 15;
    const int bloc = mb >> 3;
    float ls[2];
#pragma unroll
    for (int n = 0; n < 2; n++) ls[n] = 0.f;
#pragma unroll
    for (int i = 0; i < 2; i++) {
        int rowg = mb * 64 + wm * 32 + i * 16 + quad * 4;
        int nd = rowg & 511;
#pragma unroll
        for (int n = 0; n < 2; n++) {
            int nloc = wn * 32 + n * 16 + l16;
            int col = nt * 64 + nloc;
            float bb = beffv[col];
#pragma unroll
            for (int r = 0; r < 4; r++) {
                float x = acc[i][n][r] + bb;
                float v = LEAKY(x);
                out[(size_t)bloc * 65664 + (size_t)(nd + r + 1) * 128 + col] = v;
                ls[n] += v;
            }
        }
    }
#pragma unroll
    for (int n = 0; n < 2; n++) atomicAdd(&msS[wn * 32 + n * 16 + l16], ls[n]);
    __syncthreads();
    if (t < 64) atomicAdd(&msum[bloc * 128 + nt * 64 + t], msS[t]);
}

// depot row + final means
__global__ void k_meandep(const float* __restrict__ depot, const float* __restrict__ Wd,
                          const float* __restrict__ bd, const float* __restrict__ msum,
                          float* __restrict__ out) {
    int id = blockIdx.x * 256 + threadIdx.x;   // 4096
    int b = id >> 7, o = id & 127;
    float dep = depot[b * 2] * Wd[o] + depot[b * 2 + 1] * Wd[128 + o] + bd[o];
    out[(size_t)b * 65664 + o] = dep;
    out[2101248 + id] = (msum[id] + dep) * (1.0f / 513.0f);
}

// ---------------- launch ----------------

extern "C" void kernel_launch(void* const* d_in, const int* in_sizes, int n_in,
                              void* d_out, int out_size, void* d_ws, size_t ws_size,
                              hipStream_t stream) {
    const float* loc      = (const float*)d_in[0];
    const float* deadline = (const float*)d_in[1];
    const float* depot    = (const float*)d_in[3];
    const float* W_init   = (const float*)d_in[4];
    const float* b_init   = (const float*)d_in[5];
    const float* W_dep    = (const float*)d_in[6];
    const float* b_dep    = (const float*)d_in[7];
    const float* W_g1     = (const float*)d_in[8];
    const float* b_g1     = (const float*)d_in[9];
    const float* W_g2     = (const float*)d_in[10];
    const float* b_g2     = (const float*)d_in[11];
    const float* W_g3     = (const float*)d_in[12];
    const float* b_g3     = (const float*)d_in[13];
    const float* gamma    = (const float*)d_in[14];
    const float* beta     = (const float*)d_in[15];
    const float* W_F      = (const float*)d_in[16];
    const float* b_F      = (const float*)d_in[17];
    float* out = (float*)d_out;
    float* ws  = (float*)d_ws;

    // workspace (float offsets, all 16B aligned)
    float* dmaxv  = ws + 0;         // 4
    float* amaxf  = ws + 4;         // 4
    float* bn1    = ws + 8;         // 384
    float* bn2    = ws + 392;       // 384
    float* msum   = ws + 776;       // 4096
    float* rowsum = ws + 4872;      // 16384
    float* pmax   = ws + 21256;     // 4096
    float* sS     = ws + 25352;     // 384
    float* beffv  = ws + 25736;     // 128
    float* R      = ws + 25864;     // 8388608
    unsigned short* Lb   = (unsigned short*)(ws + 8414472);   // 8388608 u16
    unsigned short* P1   = (unsigned short*)(ws + 12608776);  // 6291456 u16
    unsigned short* P2   = (unsigned short*)(ws + 15754504);
    unsigned short* P3   = (unsigned short*)(ws + 18900232);
    unsigned short* WgT  = (unsigned short*)(ws + 22045960);  // 442368 u16
    unsigned short* WFsT = (unsigned short*)(ws + 22267144);  // 49152 u16
    unsigned short* Y2T  = (unsigned short*)(ws + 22291720);  // 6291456 u16
    unsigned short* ZT   = (unsigned short*)(ws + 25437448);
    unsigned short* F1b  = (unsigned short*)(ws + 28583176);

    hipMemsetAsync(bn1, 0, (384 + 384 + 4096) * sizeof(float), stream);

    k_dmax<<<1, 256, 0, stream>>>(deadline, dmaxv);
    k_buildR<<<4096, 256, 0, stream>>>(loc, deadline, dmaxv, R, rowsum, pmax);
    k_amax<<<1, 256, 0, stream>>>(pmax, amaxf);
    k_buildL<<<8192, 256, 0, stream>>>(R, rowsum, amaxf, Lb);
    k_F0pow<<<6144, 256, 0, stream>>>(loc, deadline, dmaxv, W_init, b_init, P1, P2, P3);
    k_prepW<<<1728, 256, 0, stream>>>(W_g1, W_g2, W_g3, WgT);

    k_ygemmT<<<dim3(3, 8, 32), 256, 0, stream>>>(WgT, P1, P2, P3, Y2T);
    k_lg1T<<<dim3(3, 8, 32), 256, 0, stream>>>(Lb, Y2T, WgT, P1, P2, P3, ZT);
    k_lg2<<<dim3(4, 6, 32), 256, 0, stream>>>(Lb, ZT, WgT, P1, P2, P3,
                                              b_g1, b_g2, b_g3, F1b, bn1, bn2);

    k_bnfin_beff<<<1, 384, 0, stream>>>(bn1, bn2, gamma, beta, W_F, b_F, sS, beffv);
    k_fold<<<192, 256, 0, stream>>>(W_F, sS, WFsT);
    k_fgemm<<<dim3(256, 2), 256, 0, stream>>>(F1b, WFsT, beffv, out, msum);
    k_meandep<<<16, 256, 0, stream>>>(depot, W_dep, b_dep, msum, out);
}

// Round 5
// 236.897 us; speedup vs baseline: 3.3390x; 1.1216x over previous
//
#include <hip/hip_runtime.h>

#define LEAKY(x) ((x) > 0.0f ? (x) : 0.01f * (x))

typedef __attribute__((ext_vector_type(8))) short bf16x8;      // MFMA A/B frag
typedef __attribute__((ext_vector_type(4))) float f32x4;       // MFMA C/D frag
typedef __attribute__((ext_vector_type(8))) unsigned short u16x8;
typedef __attribute__((ext_vector_type(4))) unsigned short u16x4;

__device__ __forceinline__ unsigned short f2bf(float f) {
    unsigned int u = __float_as_uint(f);
    unsigned int r = (u + 0x7fffu + ((u >> 16) & 1u)) >> 16;   // RNE
    return (unsigned short)r;
}
__device__ __forceinline__ float bf2f(unsigned short u) {
    return __uint_as_float(((unsigned int)u) << 16);
}

// ---------------- small builds ----------------

__global__ void k_dmax(const float* __restrict__ deadline, float* __restrict__ dmax) {
    __shared__ float red[256];
    int t = threadIdx.x;
    float m = -1e30f;
    for (int i = t; i < 16384; i += 256) m = fmaxf(m, deadline[i]);
    red[t] = m; __syncthreads();
    for (int s = 128; s > 0; s >>= 1) {
        if (t < s) red[t] = fmaxf(red[t], red[t + s]);
        __syncthreads();
    }
    if (t == 0) *dmax = red[0];
}

// rowsum + per-block max of r=1/dist; R is NOT materialized
__global__ __launch_bounds__(256) void k_rowstats(const float* __restrict__ loc,
                                                  const float* __restrict__ deadline,
                                                  const float* __restrict__ dmaxv,
                                                  float* __restrict__ rowsum, float* __restrict__ pmax) {
    int blk = blockIdx.x;                       // 0..4095
    int wave = threadIdx.x >> 6, lane = threadIdx.x & 63;
    int bi = blk * 4 + wave;                    // b*512 + i
    int b = bi >> 9, i = bi & 511;
    float invd = 1.0f / (*dmaxv);
    const float* lb = loc + b * 1024;
    const float* db = deadline + b * 512;
    float xi = lb[i * 2], yi = lb[i * 2 + 1], zi = db[i] * invd;
    float lsum = 0.f, lmax = 0.f;
    for (int j = lane; j < 512; j += 64) {
        float d0 = xi - lb[j * 2], d1 = yi - lb[j * 2 + 1], d2 = zi - db[j] * invd;
        float dd = d0 * d0 + d1 * d1 + d2 * d2;
        float r = (j == i) ? 0.f : rsqrtf(dd);
        lsum += r; lmax = fmaxf(lmax, r);
    }
    for (int off = 32; off > 0; off >>= 1) {
        lsum += __shfl_down(lsum, off);
        lmax = fmaxf(lmax, __shfl_down(lmax, off));
    }
    __shared__ float smax[4];
    if (lane == 0) { rowsum[bi] = lsum; smax[wave] = lmax; }
    __syncthreads();
    if (threadIdx.x == 0) pmax[blk] = fmaxf(fmaxf(smax[0], smax[1]), fmaxf(smax[2], smax[3]));
}

__global__ void k_amax(const float* __restrict__ pmax, float* __restrict__ amaxf) {
    __shared__ float red[256];
    int t = threadIdx.x;
    float m = 0.f;
    for (int i = t; i < 4096; i += 256) m = fmaxf(m, pmax[i]);
    red[t] = m; __syncthreads();
    for (int s = 128; s > 0; s >>= 1) {
        if (t < s) red[t] = fmaxf(red[t], red[t + s]);
        __syncthreads();
    }
    if (t == 0) *amaxf = red[0];
}

// L bf16 (symmetric), recomputing r on the fly: 4 j's per thread
__global__ void k_buildL(const float* __restrict__ loc, const float* __restrict__ deadline,
                         const float* __restrict__ dmaxv, const float* __restrict__ rowsum,
                         const float* __restrict__ amaxf, unsigned short* __restrict__ Lb) {
    int id = blockIdx.x * 256 + threadIdx.x;     // 2,097,152 threads * 4 elems
    float inv = 1.0f / (*amaxf);
    float invd = 1.0f / (*dmaxv);
    size_t e = (size_t)id * 4;
    size_t bi = e >> 9;
    int b = (int)(bi >> 9);
    int i = (int)(bi & 511);
    int j0 = (int)(e & 511);
    const float* lb = loc + b * 1024;
    const float* db = deadline + b * 512;
    float xi = lb[i * 2], yi = lb[i * 2 + 1], zi = db[i] * invd;
    float4 l01 = *(const float4*)(lb + j0 * 2);
    float4 l23 = *(const float4*)(lb + j0 * 2 + 4);
    float4 dj = *(const float4*)(db + j0);
    float diag = rowsum[bi] * inv - 1.0f;
    float jx[4] = {l01.x, l01.z, l23.x, l23.z};
    float jy[4] = {l01.y, l01.w, l23.y, l23.w};
    float jz[4] = {dj.x * invd, dj.y * invd, dj.z * invd, dj.w * invd};
    u16x4 o;
#pragma unroll
    for (int j = 0; j < 4; j++) {
        float d0 = xi - jx[j], d1 = yi - jy[j], d2 = zi - jz[j];
        float dd = d0 * d0 + d1 * d1 + d2 * d2;
        float v = (i == j0 + j) ? diag : -rsqrtf(dd) * inv;
        o[j] = f2bf(v);
    }
    *(u16x4*)(Lb + e) = o;
}

// F0 powers, bf16 row-major [16384][384] x3, 4 cols per thread
__global__ void k_F0pow(const float* __restrict__ loc, const float* __restrict__ deadline,
                        const float* __restrict__ dmaxv,
                        const float* __restrict__ Wi, const float* __restrict__ bi_,
                        unsigned short* __restrict__ P1, unsigned short* __restrict__ P2,
                        unsigned short* __restrict__ P3) {
    int id = blockIdx.x * 256 + threadIdx.x;     // 1,572,864
    int row = id / 96, c4 = (id % 96) * 4;
    float x0 = loc[row * 2], x1 = loc[row * 2 + 1], x2 = deadline[row] / (*dmaxv);
    float4 w0 = *(const float4*)(Wi + c4);
    float4 w1 = *(const float4*)(Wi + 384 + c4);
    float4 w2 = *(const float4*)(Wi + 768 + c4);
    float4 bb = *(const float4*)(bi_ + c4);
    float f[4] = {x0 * w0.x + x1 * w1.x + x2 * w2.x + bb.x,
                  x0 * w0.y + x1 * w1.y + x2 * w2.y + bb.y,
                  x0 * w0.z + x1 * w1.z + x2 * w2.z + bb.z,
                  x0 * w0.w + x1 * w1.w + x2 * w2.w + bb.w};
    u16x4 o1, o2, o3;
#pragma unroll
    for (int j = 0; j < 4; j++) {
        o1[j] = f2bf(f[j]); o2[j] = f2bf(f[j] * f[j]); o3[j] = f2bf(f[j] * f[j] * f[j]);
    }
    size_t e = (size_t)row * 384 + c4;
    *(u16x4*)(P1 + e) = o1; *(u16x4*)(P2 + e) = o2; *(u16x4*)(P3 + e) = o3;
}

// WgT[combo][n][k] = Wg{kp}[(part*384+k)*128 + n]
__global__ void k_prepW(const float* __restrict__ Wg1, const float* __restrict__ Wg2,
                        const float* __restrict__ Wg3, unsigned short* __restrict__ WgT) {
    int id = blockIdx.x * 256 + threadIdx.x;     // 442368 exact
    int combo = id / 49152, rem = id % 49152;
    int n = rem / 384, k = rem % 384;
    int kp = combo / 3, part = combo % 3;
    const float* W = (kp == 0) ? Wg1 : (kp == 1 ? Wg2 : Wg3);
    WgT[id] = f2bf(W[(part * 384 + k) * 128 + n]);
}

// ---------------- pipelined MFMA cores ----------------
// Register-prefetch + double-buffered LDS, ONE barrier per K-iter (BK=64).
// LDS rows of 64 u16 = 8 chunks of 16B; chunk XOR-swizzled by (row&7) -> conflict-free frag reads.
// 128x64 tile: 4 waves 2x2, wave tile 64x32 (4x2 frags), 16 MFMA/wave/iter.
// Up to two K-segments (different operand pairs) in one pipelined loop.

__device__ __forceinline__ void pipe128x64(
    const unsigned short* __restrict__ A0, int As0, const unsigned short* __restrict__ B0, int Bs0, int it0,
    const unsigned short* __restrict__ A1, int As1, const unsigned short* __restrict__ B1, int Bs1, int it1,
    unsigned short* AsL, unsigned short* BsL,   // 16384 / 8192 u16 (double-buffered)
    f32x4 (&acc)[4][2], int t)
{
    const int lane = t & 63, wave = t >> 6;
    const int wm = wave >> 1, wn = wave & 1;
    const int quad = lane >> 4, l16 = lane & 15;
    const int ra = t >> 1, ca = (t & 1) * 4;        // A: 128 rows, 4 chunks/thread
    const int rb = t >> 2, cb = (t & 3) * 2;        // B: 64 rows, 2 chunks/thread
    const unsigned short* Ar0 = A0 + (size_t)ra * As0;
    const unsigned short* Ar1 = A1 ? (A1 + (size_t)ra * As1) : Ar0;
    const unsigned short* Br0 = B0 + (size_t)rb * Bs0;
    const unsigned short* Br1 = B1 ? (B1 + (size_t)rb * Bs1) : Br0;
    const int total = it0 + it1;
    u16x8 pa[4], pb[2];
#pragma unroll
    for (int j = 0; j < 4; j++) pa[j] = *(const u16x8*)(Ar0 + (ca + j) * 8);
#pragma unroll
    for (int j = 0; j < 2; j++) pb[j] = *(const u16x8*)(Br0 + (cb + j) * 8);
    int buf = 0;
    for (int s = 0; s < total; s++) {
        // stage regs -> LDS[buf] (vmcnt wait for own loads lands here, after prev MFMAs)
#pragma unroll
        for (int j = 0; j < 4; j++)
            *(u16x8*)(AsL + buf * 8192 + ra * 64 + (((ca + j) ^ (ra & 7)) * 8)) = pa[j];
#pragma unroll
        for (int j = 0; j < 2; j++)
            *(u16x8*)(BsL + buf * 4096 + rb * 64 + (((cb + j) ^ (rb & 7)) * 8)) = pb[j];
        __syncthreads();
        if (s + 1 < total) {    // issue next tile's loads; they fly during the MFMAs below
            int s2 = s + 1;
            int sg = (s2 >= it0);
            int k0 = (sg ? (s2 - it0) : s2) * 64;
            const unsigned short* Ar = sg ? Ar1 : Ar0;
            const unsigned short* Br = sg ? Br1 : Br0;
#pragma unroll
            for (int j = 0; j < 4; j++) pa[j] = *(const u16x8*)(Ar + k0 + (ca + j) * 8);
#pragma unroll
            for (int j = 0; j < 2; j++) pb[j] = *(const u16x8*)(Br + k0 + (cb + j) * 8);
        }
#pragma unroll
        for (int h = 0; h < 2; h++) {
            bf16x8 af[4], bfr[2];
            int phys = ((h * 4 + quad) ^ (l16 & 7)) * 8;
#pragma unroll
            for (int i = 0; i < 4; i++)
                af[i] = *(const bf16x8*)(AsL + buf * 8192 + (wm * 64 + i * 16 + l16) * 64 + phys);
#pragma unroll
            for (int n = 0; n < 2; n++)
                bfr[n] = *(const bf16x8*)(BsL + buf * 4096 + (wn * 32 + n * 16 + l16) * 64 + phys);
#pragma unroll
            for (int i = 0; i < 4; i++)
#pragma unroll
                for (int n = 0; n < 2; n++)
                    acc[i][n] = __builtin_amdgcn_mfma_f32_16x16x32_bf16(af[i], bfr[n], acc[i][n], 0, 0, 0);
        }
        buf ^= 1;
    }
}

// 64x64 tile: wave tile 32x32 (2x2 frags), 8 MFMA/wave/iter
__device__ __forceinline__ void pipe64x64(
    const unsigned short* __restrict__ A0, int As0, const unsigned short* __restrict__ B0, int Bs0, int it0,
    unsigned short* AsL, unsigned short* BsL,   // 8192 / 8192 u16
    f32x4 (&acc)[2][2], int t)
{
    const int lane = t & 63, wave = t >> 6;
    const int wm = wave >> 1, wn = wave & 1;
    const int quad = lane >> 4, l16 = lane & 15;
    const int rb = t >> 2, cb = (t & 3) * 2;
    const unsigned short* Ar0 = A0 + (size_t)rb * As0;
    const unsigned short* Br0 = B0 + (size_t)rb * Bs0;
    u16x8 pa[2], pb[2];
#pragma unroll
    for (int j = 0; j < 2; j++) { pa[j] = *(const u16x8*)(Ar0 + (cb + j) * 8);
                                  pb[j] = *(const u16x8*)(Br0 + (cb + j) * 8); }
    int buf = 0;
    for (int s = 0; s < it0; s++) {
#pragma unroll
        for (int j = 0; j < 2; j++) {
            int phys = ((cb + j) ^ (rb & 7)) * 8;
            *(u16x8*)(AsL + buf * 4096 + rb * 64 + phys) = pa[j];
            *(u16x8*)(BsL + buf * 4096 + rb * 64 + phys) = pb[j];
        }
        __syncthreads();
        if (s + 1 < it0) {
            int k0 = (s + 1) * 64;
#pragma unroll
            for (int j = 0; j < 2; j++) { pa[j] = *(const u16x8*)(Ar0 + k0 + (cb + j) * 8);
                                          pb[j] = *(const u16x8*)(Br0 + k0 + (cb + j) * 8); }
        }
#pragma unroll
        for (int h = 0; h < 2; h++) {
            bf16x8 af[2], bfr[2];
            int phys = ((h * 4 + quad) ^ (l16 & 7)) * 8;
#pragma unroll
            for (int i = 0; i < 2; i++)
                af[i] = *(const bf16x8*)(AsL + buf * 4096 + (wm * 32 + i * 16 + l16) * 64 + phys);
#pragma unroll
            for (int n = 0; n < 2; n++)
                bfr[n] = *(const bf16x8*)(BsL + buf * 4096 + (wn * 32 + n * 16 + l16) * 64 + phys);
#pragma unroll
            for (int i = 0; i < 2; i++)
#pragma unroll
                for (int n = 0; n < 2; n++)
                    acc[i][n] = __builtin_amdgcn_mfma_f32_16x16x32_bf16(af[i], bfr[n], acc[i][n], 0, 0, 0);
        }
        buf ^= 1;
    }
}

// Y2^T[g][node] ; 1D grid 768, id = b + 32*(kp*8+nb)  (XCD-pins each batch)
__global__ __launch_bounds__(256) void k_ygemmT(
    const unsigned short* __restrict__ WgT,
    const unsigned short* __restrict__ P1, const unsigned short* __restrict__ P2,
    const unsigned short* __restrict__ P3, unsigned short* __restrict__ Y2T)
{
    __shared__ unsigned short AsL[16384], BsL[8192];
    const int t = threadIdx.x;
    const int id = blockIdx.x;
    const int b = id & 31, tt = id >> 5;
    const int kp = tt >> 3, nb = tt & 7;
    const unsigned short* P = (kp == 0) ? P1 : (kp == 1 ? P2 : P3);
    f32x4 acc[4][2];
#pragma unroll
    for (int i = 0; i < 4; i++)
#pragma unroll
        for (int n = 0; n < 2; n++) acc[i][n] = (f32x4){0.f, 0.f, 0.f, 0.f};
    pipe128x64(WgT + (size_t)(kp * 3 + 2) * 49152, 384,
               P + ((size_t)b * 512 + nb * 64) * 384, 384, 6,
               nullptr, 0, nullptr, 0, 0, AsL, BsL, acc, t);

    const int wave = t >> 6, lane = t & 63;
    const int wm = wave >> 1, wn = wave & 1;
    const int quad = lane >> 4, l16 = lane & 15;
#pragma unroll
    for (int i = 0; i < 4; i++)
#pragma unroll
        for (int n = 0; n < 2; n++) {
            int g = kp * 128 + wm * 64 + i * 16 + quad * 4;
            int node = nb * 64 + wn * 32 + n * 16 + l16;
#pragma unroll
            for (int r = 0; r < 4; r++)
                Y2T[((size_t)b * 384 + g + r) * 512 + node] = f2bf(acc[i][n][r]);
        }
}

// Z^T = Y2T·L + WgT(part1)·P ; grid 768
__global__ __launch_bounds__(256) void k_lg1T(
    const unsigned short* __restrict__ Lb, const unsigned short* __restrict__ Y2T,
    const unsigned short* __restrict__ WgT,
    const unsigned short* __restrict__ P1, const unsigned short* __restrict__ P2,
    const unsigned short* __restrict__ P3, unsigned short* __restrict__ ZT)
{
    __shared__ unsigned short AsL[16384], BsL[8192];
    const int t = threadIdx.x;
    const int id = blockIdx.x;
    const int b = id & 31, tt = id >> 5;
    const int kp = tt >> 3, nb = tt & 7;
    const unsigned short* P = (kp == 0) ? P1 : (kp == 1 ? P2 : P3);
    f32x4 acc[4][2];
#pragma unroll
    for (int i = 0; i < 4; i++)
#pragma unroll
        for (int n = 0; n < 2; n++) acc[i][n] = (f32x4){0.f, 0.f, 0.f, 0.f};
    pipe128x64(Y2T + (size_t)b * 196608 + (size_t)kp * 128 * 512, 512,
               Lb + (size_t)b * 262144 + (size_t)nb * 64 * 512, 512, 8,
               WgT + (size_t)(kp * 3 + 1) * 49152, 384,
               P + ((size_t)b * 512 + nb * 64) * 384, 384, 6, AsL, BsL, acc, t);

    const int wave = t >> 6, lane = t & 63;
    const int wm = wave >> 1, wn = wave & 1;
    const int quad = lane >> 4, l16 = lane & 15;
#pragma unroll
    for (int i = 0; i < 4; i++)
#pragma unroll
        for (int n = 0; n < 2; n++) {
            int g = kp * 128 + wm * 64 + i * 16 + quad * 4;
            int node = nb * 64 + wn * 32 + n * 16 + l16;
#pragma unroll
            for (int r = 0; r < 4; r++)
                ZT[((size_t)b * 384 + g + r) * 512 + node] = f2bf(acc[i][n][r]);
        }
}

// F1 = leaky(L·ZT + P·WgT(part0) + bias) + F0 ; fused BN sums ; grid 768, tile mb(128 nodes) x gt(64 gcols)
__global__ __launch_bounds__(256) void k_lg2(
    const unsigned short* __restrict__ Lb, const unsigned short* __restrict__ ZT,
    const unsigned short* __restrict__ WgT,
    const unsigned short* __restrict__ P1, const unsigned short* __restrict__ P2,
    const unsigned short* __restrict__ P3,
    const float* __restrict__ bg1, const float* __restrict__ bg2, const float* __restrict__ bg3,
    unsigned short* __restrict__ F1b, float* __restrict__ bn1, float* __restrict__ bn2)
{
    __shared__ unsigned short AsL[16384], BsL[8192];
    __shared__ float bnS[64], bnQ[64];
    const int t = threadIdx.x;
    const int id = blockIdx.x;
    const int b = id & 31, tt = id >> 5;
    const int mb = tt & 3, gt = tt >> 2;          // mb: node tile(128), gt: gcol tile(64) 0..5
    const int kp = gt >> 1;
    if (t < 64) { bnS[t] = 0.f; bnQ[t] = 0.f; }
    const unsigned short* P = (kp == 0) ? P1 : (kp == 1 ? P2 : P3);
    f32x4 acc[4][2];
#pragma unroll
    for (int i = 0; i < 4; i++)
#pragma unroll
        for (int n = 0; n < 2; n++) acc[i][n] = (f32x4){0.f, 0.f, 0.f, 0.f};
    pipe128x64(Lb + (size_t)b * 262144 + (size_t)mb * 128 * 512, 512,
               ZT + (size_t)b * 196608 + (size_t)gt * 64 * 512, 512, 8,
               P + ((size_t)b * 512 + mb * 128) * 384, 384,
               WgT + (size_t)(kp * 3) * 49152 + (size_t)(gt & 1) * 64 * 384, 384, 6,
               AsL, BsL, acc, t);

    const int wave = t >> 6, lane = t & 63;
    const int wm = wave >> 1, wn = wave & 1;
    const int quad = lane >> 4, l16 = lane & 15;
    const float* bg = (kp == 0) ? bg1 : (kp == 1 ? bg2 : bg3);
    float ls1[2], ls2[2];
#pragma unroll
    for (int n = 0; n < 2; n++) { ls1[n] = 0.f; ls2[n] = 0.f; }
#pragma unroll
    for (int i = 0; i < 4; i++) {
        int rowl = mb * 128 + wm * 64 + i * 16 + quad * 4;
        size_t rowg = (size_t)b * 512 + rowl;
#pragma unroll
        for (int n = 0; n < 2; n++) {
            int nloc = wn * 32 + n * 16 + l16;
            int g = gt * 64 + nloc;
            float bias = bg[(gt & 1) * 64 + nloc];
#pragma unroll
            for (int r = 0; r < 4; r++) {
                size_t idx = (rowg + r) * 384 + g;
                float c = acc[i][n][r] + bias;
                float v = LEAKY(c) + bf2f(P1[idx]);   // residual +F0
                F1b[idx] = f2bf(v);
                ls1[n] += v; ls2[n] += v * v;
            }
        }
    }
#pragma unroll
    for (int n = 0; n < 2; n++) {
        int nloc = wn * 32 + n * 16 + l16;
        atomicAdd(&bnS[nloc], ls1[n]);
        atomicAdd(&bnQ[nloc], ls2[n]);
    }
    __syncthreads();
    if (t < 64) {
        atomicAdd(&bn1[gt * 64 + t], bnS[t]);
        atomicAdd(&bn2[gt * 64 + t], bnQ[t]);
    }
}

// BN finish + effective bias for folded final GEMM
__global__ __launch_bounds__(384) void k_bnfin_beff(
    const float* __restrict__ bn1, const float* __restrict__ bn2,
    const float* __restrict__ gamma, const float* __restrict__ beta,
    const float* __restrict__ WF, const float* __restrict__ bF,
    float* __restrict__ sS, float* __restrict__ beffv)
{
    __shared__ float ttL[384];
    int c = threadIdx.x;
    float mu = bn1[c] * (1.f / 16384.f);
    float var = bn2[c] * (1.f / 16384.f) - mu * mu;
    float sc = gamma[c] / sqrtf(var + 1e-5f);
    sS[c] = sc;
    ttL[c] = beta[c] - mu * sc;
    __syncthreads();
    if (c < 128) {
        float a = bF[c];
        for (int k = 0; k < 384; k++) a += ttL[k] * WF[k * 128 + c];
        beffv[c] = a;
    }
}

// WFsT[n][k] = W_F[k][n] * sS[k]
__global__ void k_fold(const float* __restrict__ WF, const float* __restrict__ sS,
                       unsigned short* __restrict__ WFsT) {
    int id = blockIdx.x * 256 + threadIdx.x;   // 49152
    int n = id / 384, k = id % 384;
    WFsT[id] = f2bf(WF[k * 128 + n] * sS[k]);
}

// out rows 1..512 = leaky(F1b @ WFsT + beff); fused column-sum partials
// 1D grid 512: id = b + 32*(seg*2+nt)
__global__ __launch_bounds__(256) void k_fgemm(
    const unsigned short* __restrict__ F1b, const unsigned short* __restrict__ WFsT,
    const float* __restrict__ beffv, float* __restrict__ out, float* __restrict__ msum)
{
    __shared__ unsigned short AsL[8192], BsL[8192];
    __shared__ float msS[64];
    const int t = threadIdx.x;
    const int id = blockIdx.x;
    const int b = id & 31, tt = id >> 5;
    const int seg = tt >> 1, nt = tt & 1;
    if (t < 64) msS[t] = 0.f;
    f32x4 acc[2][2];
#pragma unroll
    for (int i = 0; i < 2; i++)
#pragma unroll
        for (int n = 0; n < 2; n++) acc[i][n] = (f32x4){0.f, 0.f, 0.f, 0.f};
    pipe64x64(F1b + ((size_t)b * 512 + seg * 64) * 384, 384,
              WFsT + (size_t)nt * 64 * 384, 384, 6, AsL, BsL, acc, t);

    const int wave = t >> 6, lane = t & 63;
    const int wm = wave >> 1, wn = wave & 1;
    const int quad = lane >> 4, l16 = lane & 15;
    float ls[2];
#pragma unroll
    for (int n = 0; n < 2; n++) ls[n] = 0.f;
#pragma unroll
    for (int i = 0; i < 2; i++) {
        int nd = seg * 64 + wm * 32 + i * 16 + quad * 4;
#pragma unroll
        for (int n = 0; n < 2; n++) {
            int col = nt * 64 + wn * 32 + n * 16 + l16;
            float bb = beffv[col];
#pragma unroll
            for (int r = 0; r < 4; r++) {
                float x = acc[i][n][r] + bb;
                float v = LEAKY(x);
                out[(size_t)b * 65664 + (size_t)(nd + r + 1) * 128 + col] = v;
                ls[n] += v;
            }
        }
    }
#pragma unroll
    for (int n = 0; n < 2; n++) atomicAdd(&msS[wn * 32 + n * 16 + l16], ls[n]);
    __syncthreads();
    if (t < 64) atomicAdd(&msum[b * 128 + nt * 64 + t], msS[t]);
}

// depot row + final means
__global__ void k_meandep(const float* __restrict__ depot, const float* __restrict__ Wd,
                          const float* __restrict__ bd, const float* __restrict__ msum,
                          float* __restrict__ out) {
    int id = blockIdx.x * 256 + threadIdx.x;   // 4096
    int b = id >> 7, o = id & 127;
    float dep = depot[b * 2] * Wd[o] + depot[b * 2 + 1] * Wd[128 + o] + bd[o];
    out[(size_t)b * 65664 + o] = dep;
    out[2101248 + id] = (msum[id] + dep) * (1.0f / 513.0f);
}

// ---------------- launch ----------------

extern "C" void kernel_launch(void* const* d_in, const int* in_sizes, int n_in,
                              void* d_out, int out_size, void* d_ws, size_t ws_size,
                              hipStream_t stream) {
    const float* loc      = (const float*)d_in[0];
    const float* deadline = (const float*)d_in[1];
    const float* depot    = (const float*)d_in[3];
    const float* W_init   = (const float*)d_in[4];
    const float* b_init   = (const float*)d_in[5];
    const float* W_dep    = (const float*)d_in[6];
    const float* b_dep    = (const float*)d_in[7];
    const float* W_g1     = (const float*)d_in[8];
    const float* b_g1     = (const float*)d_in[9];
    const float* W_g2     = (const float*)d_in[10];
    const float* b_g2     = (const float*)d_in[11];
    const float* W_g3     = (const float*)d_in[12];
    const float* b_g3     = (const float*)d_in[13];
    const float* gamma    = (const float*)d_in[14];
    const float* beta     = (const float*)d_in[15];
    const float* W_F      = (const float*)d_in[16];
    const float* b_F      = (const float*)d_in[17];
    float* out = (float*)d_out;
    float* ws  = (float*)d_ws;

    // workspace (float offsets, 16B aligned); ~23.3M floats ~= 93 MB
    float* dmaxv  = ws + 0;         // 4
    float* amaxf  = ws + 4;         // 4
    float* bn1    = ws + 8;         // 384
    float* bn2    = ws + 392;       // 384
    float* msum   = ws + 776;       // 4096
    float* rowsum = ws + 4872;      // 16384
    float* pmax   = ws + 21256;     // 4096
    float* sS     = ws + 25352;     // 384
    float* beffv  = ws + 25736;     // 128
    unsigned short* Lb   = (unsigned short*)(ws + 25864);     // 8388608 u16
    unsigned short* P1   = (unsigned short*)(ws + 4220168);   // 6291456 u16
    unsigned short* P2   = (unsigned short*)(ws + 7365896);
    unsigned short* P3   = (unsigned short*)(ws + 10511624);
    unsigned short* WgT  = (unsigned short*)(ws + 13657352);  // 442368 u16
    unsigned short* WFsT = (unsigned short*)(ws + 13878536);  // 49152 u16
    unsigned short* Y2T  = (unsigned short*)(ws + 13903112);  // 6291456 u16
    unsigned short* ZT   = (unsigned short*)(ws + 17048840);
    unsigned short* F1b  = (unsigned short*)(ws + 20194568);

    hipMemsetAsync(bn1, 0, (384 + 384 + 4096) * sizeof(float), stream);

    k_dmax<<<1, 256, 0, stream>>>(deadline, dmaxv);
    k_rowstats<<<4096, 256, 0, stream>>>(loc, deadline, dmaxv, rowsum, pmax);
    k_amax<<<1, 256, 0, stream>>>(pmax, amaxf);
    k_buildL<<<8192, 256, 0, stream>>>(loc, deadline, dmaxv, rowsum, amaxf, Lb);
    k_F0pow<<<6144, 256, 0, stream>>>(loc, deadline, dmaxv, W_init, b_init, P1, P2, P3);
    k_prepW<<<1728, 256, 0, stream>>>(W_g1, W_g2, W_g3, WgT);

    k_ygemmT<<<768, 256, 0, stream>>>(WgT, P1, P2, P3, Y2T);
    k_lg1T<<<768, 256, 0, stream>>>(Lb, Y2T, WgT, P1, P2, P3, ZT);
    k_lg2<<<768, 256, 0, stream>>>(Lb, ZT, WgT, P1, P2, P3,
                                   b_g1, b_g2, b_g3, F1b, bn1, bn2);

    k_bnfin_beff<<<1, 384, 0, stream>>>(bn1, bn2, gamma, beta, W_F, b_F, sS, beffv);
    k_fold<<<192, 256, 0, stream>>>(W_F, sS, WFsT);
    k_fgemm<<<512, 256, 0, stream>>>(F1b, WFsT, beffv, out, msum);
    k_meandep<<<16, 256, 0, stream>>>(depot, W_dep, b_dep, msum, out);
}